// Round 13
// baseline (978.057 us; speedup 1.0000x reference)
//
#include <hip/hip_runtime.h>
#include <hip/hip_bf16.h>
#include <cstdint>
#include <cstddef>

#define NNODES 100000
#define DFEAT 128
#define KHOP 8
#define FAN1 1152        // D*(K+1)
#define HIDN 512
#define OUTD 32
#define NEDGE 1600000
#define BN_EPS 1e-5f
#define DEG_EPS 1e-8f
#define FIXSCALE 67108864.0f   // 2^26

using short8 = __attribute__((ext_vector_type(8))) short;
using f32x4  = __attribute__((ext_vector_type(4))) float;

__device__ __forceinline__ float bf16lo(uint32_t u) { return __uint_as_float(u << 16); }
__device__ __forceinline__ float bf16hi(uint32_t u) { return __uint_as_float(u & 0xffff0000u); }
__device__ __forceinline__ float bf16s(short x) {
    return __uint_as_float(((uint32_t)(uint16_t)x) << 16);
}
__device__ __forceinline__ uint32_t packbf(float a, float b) {
    uint32_t lo = __bfloat16_as_ushort(__float2bfloat16(a));
    uint32_t hi = __bfloat16_as_ushort(__float2bfloat16(b));
    return lo | (hi << 16);
}

__device__ __forceinline__ void gload16(const void* g, void* l) {
    __builtin_amdgcn_global_load_lds(
        (const __attribute__((address_space(1))) uint32_t*)g,
        (__attribute__((address_space(3))) uint32_t*)l, 16, 0, 0);
}

struct Blk3 { const __hip_bfloat16* p[3]; };

// ------ edge pass 1: ONE packed 64-bit atomic = {cnt:16 | deg_fix:48} ------
__global__ __launch_bounds__(256) void edge_kernel(
    const int* __restrict__ ei, const float* __restrict__ coor,
    const float* __restrict__ theta, const int* __restrict__ mm,
    unsigned long long* __restrict__ packed, unsigned short* __restrict__ rank)
{
    int e = blockIdx.x * 256 + threadIdx.x;
    if (e >= NEDGE) return;
    float tom = theta[0] / (float)mm[0];
    int r = ei[e], c = ei[NEDGE + e];
    float2 pr = *(const float2*)(coor + 2*(size_t)r);
    float2 pc = *(const float2*)(coor + 2*(size_t)c);
    float dx = pr.x - pc.x, dy = pr.y - pc.y;
    float w = expf(-(dx*dx + dy*dy) * tom);
    unsigned long long enc = (1ULL << 48)
        | (unsigned long long)(unsigned int)__float2uint_rn(w * FIXSCALE);
    unsigned long long old = atomicAdd(&packed[r], enc);
    rank[e] = (unsigned short)(old >> 48);
}

// ---------------- 3-phase parallel scan (reads counts from packed) --------
__global__ __launch_bounds__(1024) void scan_local(
    const unsigned long long* __restrict__ packed, int* __restrict__ row_ptr,
    int* __restrict__ bsum, int n)
{
    __shared__ int wsum[16];
    int b = blockIdx.x, tid = threadIdx.x;
    int i = b * 1024 + tid;
    int lane = tid & 63, wv = tid >> 6;
    int v = (i < n) ? (int)(packed[i] >> 48) : 0;
    #pragma unroll
    for (int off = 1; off < 64; off <<= 1) {
        int t = __shfl_up(v, off, 64);
        if (lane >= off) v += t;
    }
    if (lane == 63) wsum[wv] = v;
    __syncthreads();
    if (tid < 16) {
        int t = wsum[tid];
        #pragma unroll
        for (int off = 1; off < 16; off <<= 1) {
            int u = __shfl_up(t, off, 64);
            if (tid >= off) t += u;
        }
        wsum[tid] = t;
    }
    __syncthreads();
    int incl = v + ((wv == 0) ? 0 : wsum[wv - 1]);
    if (i < n) row_ptr[i + 1] = incl;
    if (tid == 0) bsum[b] = wsum[15];
}

__global__ __launch_bounds__(128) void scan_carry(int* __restrict__ bsum, int n)
{
    __shared__ int ws[2];
    int tid = threadIdx.x, lane = tid & 63, wv = tid >> 6;
    int v = (tid < n) ? bsum[tid] : 0;
    int incl = v;
    #pragma unroll
    for (int off = 1; off < 64; off <<= 1) {
        int t = __shfl_up(incl, off, 64);
        if (lane >= off) incl += t;
    }
    if (lane == 63) ws[wv] = incl;
    __syncthreads();
    int excl = incl - v + ((wv == 0) ? 0 : ws[0]);
    if (tid < n) bsum[tid] = excl;
}

__global__ __launch_bounds__(256) void scan_add(
    const int* __restrict__ bsum, int* __restrict__ row_ptr, int n)
{
    int i = blockIdx.x * 256 + threadIdx.x;
    if (i == 0) row_ptr[0] = 0;
    if (i < n) row_ptr[i + 1] += bsum[i >> 10];
}

// ------ edge pass 2: ATOMIC-FREE fill; packed edge data {col, nrm} --------
__global__ __launch_bounds__(256) void fill_kernel(
    const int* __restrict__ ei, const float* __restrict__ coor,
    const float* __restrict__ theta, const int* __restrict__ mm,
    const unsigned long long* __restrict__ packed,
    const unsigned short* __restrict__ rank, const int* __restrict__ row_ptr,
    uint2* __restrict__ edat)
{
    int e = blockIdx.x * 256 + threadIdx.x;
    if (e >= NEDGE) return;
    float tom = theta[0] / (float)mm[0];
    int r = ei[e], c = ei[NEDGE + e];
    float2 pr = *(const float2*)(coor + 2*(size_t)r);
    float2 pc = *(const float2*)(coor + 2*(size_t)c);
    float dx = pr.x - pc.x, dy = pr.y - pc.y;
    float w = expf(-(dx*dx + dy*dy) * tom);
    float deg = (float)(double)(packed[r] & 0xFFFFFFFFFFFFULL) * (1.0f / FIXSCALE);
    int pos = row_ptr[r] + rank[e];
    uint2 d;
    d.x = (unsigned)c;
    d.y = __float_as_uint(w / (deg + DEG_EPS));
    edat[pos] = d;
}

// ---------------- cast feature -> bf16 slot ([N,128]) ----------------
__global__ __launch_bounds__(256) void cast_feat_kernel(
    const float* __restrict__ f, __hip_bfloat16* __restrict__ x0)
{
    int i = blockIdx.x * 256 + threadIdx.x;      // over N*64 float2 units
    int node = i >> 6, l2 = i & 63;
    if (node >= NNODES) return;
    float2 v = *(const float2*)(f + (size_t)node * DFEAT + l2 * 2);
    __hip_bfloat162 hb;
    hb.x = __float2bfloat16(v.x);
    hb.y = __float2bfloat16(v.y);
    *(__hip_bfloat162*)(x0 + (size_t)node * DFEAT + l2 * 2) = hb;
}

// ---------------- cast W1 -> bf16 ----------------
__global__ __launch_bounds__(256) void cast_w1_kernel(
    const float* __restrict__ w1, __hip_bfloat16* __restrict__ o)
{
    int i = blockIdx.x * 256 + threadIdx.x;
    if (i < HIDN * FAN1) o[i] = __float2bfloat16(w1[i]);
}

// ------- prop hop: wave/node; 4 quarter-lanes own edge streams, 16B/lane ---
__global__ __launch_bounds__(256) void prop_kernel(
    const __hip_bfloat16* __restrict__ x, __hip_bfloat16* __restrict__ y,
    const int* __restrict__ row_ptr, const uint2* __restrict__ edat)
{
    int gw = (blockIdx.x * 256 + threadIdx.x) >> 6;
    if (gw >= NNODES) return;
    int lane = threadIdx.x & 63;
    int q = lane >> 4, sl = lane & 15;
    int beg = row_ptr[gw], end = row_ptr[gw + 1];
    float a0 = 0.f, a1 = 0.f, a2 = 0.f, a3 = 0.f;
    float a4 = 0.f, a5 = 0.f, a6 = 0.f, a7 = 0.f;
    int e = beg + q;
    for (; e + 12 < end; e += 16) {   // this lane: e, e+4, e+8, e+12
        uint2 e0 = edat[e], e1 = edat[e + 4], e2 = edat[e + 8], e3 = edat[e + 12];
        float w0 = __uint_as_float(e0.y), w1 = __uint_as_float(e1.y);
        float w2 = __uint_as_float(e2.y), w3 = __uint_as_float(e3.y);
        uint4 u0 = *(const uint4*)(x + (size_t)e0.x * DFEAT + sl * 8);
        uint4 u1 = *(const uint4*)(x + (size_t)e1.x * DFEAT + sl * 8);
        uint4 u2 = *(const uint4*)(x + (size_t)e2.x * DFEAT + sl * 8);
        uint4 u3 = *(const uint4*)(x + (size_t)e3.x * DFEAT + sl * 8);
        a0 += w0 * bf16lo(u0.x); a1 += w0 * bf16hi(u0.x);
        a2 += w0 * bf16lo(u0.y); a3 += w0 * bf16hi(u0.y);
        a4 += w0 * bf16lo(u0.z); a5 += w0 * bf16hi(u0.z);
        a6 += w0 * bf16lo(u0.w); a7 += w0 * bf16hi(u0.w);
        a0 += w1 * bf16lo(u1.x); a1 += w1 * bf16hi(u1.x);
        a2 += w1 * bf16lo(u1.y); a3 += w1 * bf16hi(u1.y);
        a4 += w1 * bf16lo(u1.z); a5 += w1 * bf16hi(u1.z);
        a6 += w1 * bf16lo(u1.w); a7 += w1 * bf16hi(u1.w);
        a0 += w2 * bf16lo(u2.x); a1 += w2 * bf16hi(u2.x);
        a2 += w2 * bf16lo(u2.y); a3 += w2 * bf16hi(u2.y);
        a4 += w2 * bf16lo(u2.z); a5 += w2 * bf16hi(u2.z);
        a6 += w2 * bf16lo(u2.w); a7 += w2 * bf16hi(u2.w);
        a0 += w3 * bf16lo(u3.x); a1 += w3 * bf16hi(u3.x);
        a2 += w3 * bf16lo(u3.y); a3 += w3 * bf16hi(u3.y);
        a4 += w3 * bf16lo(u3.z); a5 += w3 * bf16hi(u3.z);
        a6 += w3 * bf16lo(u3.w); a7 += w3 * bf16hi(u3.w);
    }
    for (; e < end; e += 4) {
        uint2 e0 = edat[e];
        float w0 = __uint_as_float(e0.y);
        uint4 u0 = *(const uint4*)(x + (size_t)e0.x * DFEAT + sl * 8);
        a0 += w0 * bf16lo(u0.x); a1 += w0 * bf16hi(u0.x);
        a2 += w0 * bf16lo(u0.y); a3 += w0 * bf16hi(u0.y);
        a4 += w0 * bf16lo(u0.z); a5 += w0 * bf16hi(u0.z);
        a6 += w0 * bf16lo(u0.w); a7 += w0 * bf16hi(u0.w);
    }
    a0 += __shfl_xor(a0, 16, 64); a0 += __shfl_xor(a0, 32, 64);
    a1 += __shfl_xor(a1, 16, 64); a1 += __shfl_xor(a1, 32, 64);
    a2 += __shfl_xor(a2, 16, 64); a2 += __shfl_xor(a2, 32, 64);
    a3 += __shfl_xor(a3, 16, 64); a3 += __shfl_xor(a3, 32, 64);
    a4 += __shfl_xor(a4, 16, 64); a4 += __shfl_xor(a4, 32, 64);
    a5 += __shfl_xor(a5, 16, 64); a5 += __shfl_xor(a5, 32, 64);
    a6 += __shfl_xor(a6, 16, 64); a6 += __shfl_xor(a6, 32, 64);
    a7 += __shfl_xor(a7, 16, 64); a7 += __shfl_xor(a7, 32, 64);
    if (q == 0) {
        uint4 o;
        o.x = packbf(a0, a1);
        o.y = packbf(a2, a3);
        o.z = packbf(a4, a5);
        o.w = packbf(a6, a7);
        *(uint4*)(y + (size_t)gw * DFEAT + sl * 8) = o;
    }
}

// ---- fc1: 128x128 block = 4 INDEPENDENT 64x64 wave-GEMMs, wave-private
//      LDS dbuf (16KB/wave), ZERO mid-loop barriers, per-wave vmcnt(8).
//      h1 N-BLOCK-MAJOR [4][N][128] streaming epilogue. ----
// grid 3128 = 8 XCD chunks x 391; lid = (pid%8)*391 + pid/8; n-fast
// mode bit0 = RMW accumulate, bit1 = finalize (bias+lrelu+stats)
__global__ __launch_bounds__(256) void fc1_kernel(
    Blk3 blks, const __hip_bfloat16* __restrict__ w1,
    const float* __restrict__ b1, __hip_bfloat16* __restrict__ h1b,
    float* __restrict__ gsum, float* __restrict__ gsq,
    int nkt, int kb0, int mode)
{
    __shared__ char smem[66560];   // 4 waves x 16KB private dbuf; epilogue: 32K tile + 1K stats
    int pid = blockIdx.x;
    int lid = (pid & 7) * 391 + (pid >> 3);   // XCD-chunked bijective remap
    int n0 = (lid & 3) * 128;
    int m0 = (lid >> 2) * 128;
    int tid = threadIdx.x, lane = tid & 63, wv = tid >> 6;
    int wr = wv >> 1, wc = wv & 1;
    char* W = smem + wv * 16384;              // this wave's private region

    f32x4 acc[4][4];
    #pragma unroll
    for (int i = 0; i < 4; ++i)
        #pragma unroll
        for (int j = 0; j < 4; ++j)
            acc[i][j] = (f32x4){0.f, 0.f, 0.f, 0.f};

// Wave-private staging: this wave's 64 A-rows and 64 B-rows for K-step ktv.
// buf hb: A at W+hb*8192, B at W+hb*8192+4096. 8 gloads (4 A + 4 B).
#define STAGE(hb, ktv) do {                                                   \
        const __hip_bfloat16* xp = blks.p[(ktv) >> 2];                        \
        int koff_ = ((ktv) & 3) * 32;                                         \
        int kglob_ = (kb0 + ((ktv) >> 2)) * 128 + koff_;                      \
        char* Ab_ = W + (hb) * 8192;                                          \
        char* Bb_ = Ab_ + 4096;                                               \
        _Pragma("unroll")                                                     \
        for (int l = 0; l < 4; ++l) {                                         \
            int u = l * 64 + lane;                                            \
            int row_ = u >> 2, qq_ = u & 3;                                   \
            gload16(xp + (size_t)(m0 + wr * 64 + row_) * DFEAT + koff_ + qq_ * 8, \
                    Ab_ + u * 16);                                            \
        }                                                                     \
        _Pragma("unroll")                                                     \
        for (int l = 0; l < 4; ++l) {                                         \
            int u = l * 64 + lane;                                            \
            int row_ = u >> 2, qq_ = u & 3;                                   \
            gload16(w1 + (size_t)(n0 + wc * 64 + row_) * FAN1 + kglob_ + qq_ * 8, \
                    Bb_ + u * 16);                                            \
        }                                                                     \
    } while (0)

    STAGE(0, 0);
    for (int kt = 0; kt < nkt; ++kt) {        // runtime bound; NO barriers
        int cur = kt & 1;
        if (kt + 1 < nkt) {
            STAGE(cur ^ 1, kt + 1);
            asm volatile("s_waitcnt vmcnt(8)" ::: "memory");   // cur's 8 done
        } else {
            asm volatile("s_waitcnt vmcnt(0)" ::: "memory");
        }
        char* Ab = W + cur * 8192;
        char* Bb = Ab + 4096;
        short8 af[4], bfr[4];
        #pragma unroll
        for (int i = 0; i < 4; ++i)
            af[i] = *(const short8*)(Ab + (i * 16 + (lane & 15)) * 64 + (lane >> 4) * 16);
        #pragma unroll
        for (int j = 0; j < 4; ++j)
            bfr[j] = *(const short8*)(Bb + (j * 16 + (lane & 15)) * 64 + (lane >> 4) * 16);
        #pragma unroll
        for (int j = 0; j < 4; ++j)
            #pragma unroll
            for (int i = 0; i < 4; ++i)
                acc[i][j] = __builtin_amdgcn_mfma_f32_16x16x32_bf16(af[i], bfr[j], acc[i][j], 0, 0, 0);
    }
#undef STAGE

    // ---- epilogue: LDS transpose; STREAMING store to blocked h1 ----
    __syncthreads();                          // all waves done with private bufs
    __hip_bfloat16* tile = (__hip_bfloat16*)smem;      // [128][128] = 32KB
    float* lsum = (float*)(smem + 65536);              // [128]
    float* lsq  = lsum + 128;
    bool fin = (mode & 2) != 0;
    if (fin && tid < 128) { lsum[tid] = 0.f; lsq[tid] = 0.f; }
    #pragma unroll
    for (int i = 0; i < 4; ++i) {
        #pragma unroll
        for (int j = 0; j < 4; ++j) {
            int col = wc * 64 + j * 16 + (lane & 15);
            #pragma unroll
            for (int r = 0; r < 4; ++r) {
                int row = wr * 64 + i * 16 + (lane >> 4) * 4 + r;
                tile[row * 128 + col] = __float2bfloat16(acc[i][j][r]);
            }
        }
    }
    __syncthreads();

    int cu = tid & 15, tr = tid >> 4;
    float bias[8];
    float s[8], q[8];
    #pragma unroll
    for (int e = 0; e < 8; ++e) { s[e] = 0.f; q[e] = 0.f; }
    if (fin) {
        #pragma unroll
        for (int e = 0; e < 8; ++e) bias[e] = b1[n0 + cu * 8 + e];
    }
    size_t blkbase = (size_t)(n0 >> 7) * NNODES * 128;
    for (int p = 0; p < 8; ++p) {
        int row = p * 16 + tr;
        int gm = m0 + row;
        if (gm >= NNODES) continue;
        short8 fresh = *(const short8*)(tile + row * 128 + cu * 8);
        size_t gidx = blkbase + (size_t)gm * 128 + cu * 8;   // streaming: 256B/row
        float v[8];
        #pragma unroll
        for (int e = 0; e < 8; ++e) v[e] = bf16s(fresh[e]);
        if (mode & 1) {
            short8 prev = *(const short8*)(h1b + gidx);
            #pragma unroll
            for (int e = 0; e < 8; ++e) v[e] += bf16s(prev[e]);
        }
        if (fin) {
            #pragma unroll
            for (int e = 0; e < 8; ++e) {
                float t = v[e] + bias[e];
                t = (t > 0.f) ? t : 0.2f * t;
                v[e] = t;
                s[e] += t;
                q[e] += t * t;
            }
        }
        short8 outv;
        #pragma unroll
        for (int e = 0; e < 8; ++e) outv[e] = (short)__bfloat16_as_ushort(__float2bfloat16(v[e]));
        *(short8*)(h1b + gidx) = outv;
    }
    if (fin) {
        #pragma unroll
        for (int e = 0; e < 8; ++e) {
            atomicAdd(&lsum[cu * 8 + e], s[e]);
            atomicAdd(&lsq[cu * 8 + e], q[e]);
        }
        __syncthreads();
        if (tid < 128) {
            atomicAdd(&gsum[n0 + tid], lsum[tid]);
            atomicAdd(&gsq[n0 + tid], lsq[tid]);
        }
    }
}

// ---------------- BN finalize: fold into W2 + const vector ----------------
__global__ __launch_bounds__(512) void bn_finalize(
    const float* __restrict__ gsum, const float* __restrict__ gsq,
    const float* __restrict__ gamma, const float* __restrict__ beta,
    const float* __restrict__ w2, const float* __restrict__ b2,
    __hip_bfloat16* __restrict__ w2s, float* __restrict__ cvec)
{
    __shared__ float ts[HIDN];
    int tid = threadIdx.x;              // 512 threads
    float mu = gsum[tid] * (1.0f / NNODES);
    float var = gsq[tid] * (1.0f / NNODES) - mu * mu;
    float s = gamma[tid] * rsqrtf(var + BN_EPS);
    float t = beta[tid] - mu * s;
    ts[tid] = t;
    for (int o = 0; o < OUTD; ++o)
        w2s[o * HIDN + tid] = __float2bfloat16(w2[o * HIDN + tid] * s);
    __syncthreads();
    int lane = tid & 63, wv = tid >> 6; // 8 waves
    for (int o = wv; o < OUTD; o += 8) {
        float p = 0.f;
        for (int j = lane; j < HIDN; j += 64) p += ts[j] * w2[o * HIDN + j];
        #pragma unroll
        for (int off = 32; off; off >>= 1) p += __shfl_xor(p, off, 64);
        if (lane == 0) cvec[o] = p + b2[o];
    }
}

// ---------------- fc2: blocked h1 [4][N][128] x W2^T -> out [N,32] ---------
__global__ __launch_bounds__(256) void fc2_kernel(
    const __hip_bfloat16* __restrict__ h1b, const __hip_bfloat16* __restrict__ w2s,
    const float* __restrict__ cvec, float* __restrict__ out)
{
    int gw = (blockIdx.x * 256 + threadIdx.x) >> 6;
    if (gw >= NNODES / 16) return;
    int lane = threadIdx.x & 63;
    int m0 = gw * 16;
    f32x4 acc[2];
    acc[0] = (f32x4){0.f, 0.f, 0.f, 0.f};
    acc[1] = (f32x4){0.f, 0.f, 0.f, 0.f};
    #pragma unroll
    for (int kt = 0; kt < HIDN / 32; ++kt) {
        int k0 = kt * 32;
        short8 a = *(const short8*)(h1b
            + ((size_t)(kt >> 2) * NNODES + (m0 + (lane & 15))) * 128
            + (kt & 3) * 32 + (lane >> 4) * 8);
        #pragma unroll
        for (int j = 0; j < 2; ++j) {
            short8 b = *(const short8*)(w2s + (size_t)(j * 16 + (lane & 15)) * HIDN + k0 + (lane >> 4) * 8);
            acc[j] = __builtin_amdgcn_mfma_f32_16x16x32_bf16(a, b, acc[j], 0, 0, 0);
        }
    }
    #pragma unroll
    for (int j = 0; j < 2; ++j) {
        int col = j * 16 + (lane & 15);
        float cadd = cvec[col];
        #pragma unroll
        for (int r = 0; r < 4; ++r) {
            int row = m0 + (lane >> 4) * 4 + r;
            out[(size_t)row * OUTD + col] = acc[j][r] + cadd;
        }
    }
}

// ---------------- host ----------------
struct Ptrs {
    float *gsum, *gsq, *cvec;
    int *row_ptr, *bsum;
    unsigned long long* packed;
    unsigned short* rank;
    uint2* edat;
    __hip_bfloat16 *slot[3], *h1acc, *w1b, *w2s;
};

static size_t layout(char* base, Ptrs& P) {
    char* p = base;
    auto take = [&](size_t b) {
        char* q = (char*)(((uintptr_t)p + 255) & ~(uintptr_t)255);
        p = q + b;
        return q;
    };
    P.packed  = (unsigned long long*)take((size_t)NNODES * 8);
    P.rank    = (unsigned short*)take((size_t)NEDGE * 2);
    P.row_ptr = (int*)  take((size_t)(NNODES + 1) * 4);
    P.bsum    = (int*)  take(128 * 4);
    P.edat    = (uint2*)take((size_t)NEDGE * 8);
    P.h1acc   = (__hip_bfloat16*)take((size_t)NNODES * HIDN * 2 + 65536);
    P.w1b     = (__hip_bfloat16*)take((size_t)HIDN * FAN1 * 2);
    P.w2s     = (__hip_bfloat16*)take((size_t)OUTD * HIDN * 2);
    P.gsum    = (float*)take(HIDN * 4);
    P.gsq     = (float*)take(HIDN * 4);
    P.cvec    = (float*)take(OUTD * 4);
    for (int i = 0; i < 3; ++i)   // +32KB pad: fc1 A-stage overreads last m-tile
        P.slot[i] = (__hip_bfloat16*)take((size_t)NNODES * DFEAT * 2 + 32768);
    return (size_t)(p - base);
}

extern "C" void kernel_launch(void* const* d_in, const int* in_sizes, int n_in,
                              void* d_out, int out_size, void* d_ws, size_t ws_size,
                              hipStream_t stream)
{
    const float* feature = (const float*)d_in[0];
    const float* coor    = (const float*)d_in[1];
    const float* theta   = (const float*)d_in[2];
    const float* W1      = (const float*)d_in[3];
    const float* b1      = (const float*)d_in[4];
    const float* gamma   = (const float*)d_in[5];
    const float* beta    = (const float*)d_in[6];
    const float* W2      = (const float*)d_in[7];
    const float* b2      = (const float*)d_in[8];
    const int*   ei      = (const int*)d_in[9];
    const int*   mm      = (const int*)d_in[10];
    float* out = (float*)d_out;
    (void)in_sizes; (void)n_in; (void)out_size; (void)ws_size;

    Ptrs P;
    layout((char*)d_ws, P);

    hipMemsetAsync(P.packed, 0, (size_t)NNODES * 8, stream);
    hipMemsetAsync(P.gsum,   0, HIDN * 4, stream);
    hipMemsetAsync(P.gsq,    0, HIDN * 4, stream);

    int eb = (NEDGE + 255) / 256;
    int nchunk = (NNODES + 1023) / 1024;
    edge_kernel<<<eb, 256, 0, stream>>>(ei, coor, theta, mm, P.packed, P.rank);
    scan_local<<<nchunk, 1024, 0, stream>>>(P.packed, P.row_ptr, P.bsum, NNODES);
    scan_carry<<<1, 128, 0, stream>>>(P.bsum, nchunk);
    scan_add<<<(NNODES + 255) / 256, 256, 0, stream>>>(P.bsum, P.row_ptr, NNODES);
    fill_kernel<<<eb, 256, 0, stream>>>(ei, coor, theta, mm, P.packed, P.rank,
                                        P.row_ptr, P.edat);

    cast_w1_kernel<<<(HIDN * FAN1 + 255) / 256, 256, 0, stream>>>(W1, P.w1b);
    cast_feat_kernel<<<(NNODES * 64) / 256, 256, 0, stream>>>(feature, P.slot[0]);

    int pb = (NNODES * 64) / 256;
    int fgrid = 8 * 391;      // 3128 blocks, XCD-chunk swizzled in-kernel

    auto launch_fc1 = [&](int kb0, int mode) {
        Blk3 b;
        for (int i = 0; i < 3; ++i) b.p[i] = P.slot[i];
        fc1_kernel<<<fgrid, 256, 0, stream>>>(b, P.w1b, b1, P.h1acc,
                                              P.gsum, P.gsq, 12, kb0, mode);
    };

    // blocks 0..8 rotate through slots 0,1,2; GEMM after every 3rd block ready
    for (int k = 1; k <= KHOP; ++k) {
        prop_kernel<<<pb, 256, 0, stream>>>(P.slot[(k - 1) % 3],
                                            P.slot[k % 3],
                                            P.row_ptr, P.edat);
        if (k == 2) launch_fc1(0, 0);     // blocks 0,1,2 in slots 0,1,2
        if (k == 5) launch_fc1(3, 1);     // blocks 3,4,5 in slots 0,1,2
    }
    launch_fc1(6, 3);                     // blocks 6,7,8 in slots 0,1,2

    bn_finalize<<<1, 512, 0, stream>>>(P.gsum, P.gsq, gamma, beta, W2, b2,
                                       P.w2s, P.cvec);
    fc2_kernel<<<(NNODES / 16 * 64 + 255) / 256, 256, 0, stream>>>(P.h1acc, P.w2s,
                                                                   P.cvec, out);
}

// Round 14
// 904.319 us; speedup vs baseline: 1.0815x; 1.0815x over previous
//
#include <hip/hip_runtime.h>
#include <hip/hip_bf16.h>
#include <cstdint>
#include <cstddef>

#define NNODES 100000
#define DFEAT 128
#define KHOP 8
#define FAN1 1152        // D*(K+1)
#define HIDN 512
#define OUTD 32
#define NEDGE 1600000
#define BN_EPS 1e-5f
#define DEG_EPS 1e-8f
#define FIXSCALE 67108864.0f   // 2^26

using short8 = __attribute__((ext_vector_type(8))) short;
using f32x4  = __attribute__((ext_vector_type(4))) float;

__device__ __forceinline__ float bf16lo(uint32_t u) { return __uint_as_float(u << 16); }
__device__ __forceinline__ float bf16hi(uint32_t u) { return __uint_as_float(u & 0xffff0000u); }
__device__ __forceinline__ float bf16s(short x) {
    return __uint_as_float(((uint32_t)(uint16_t)x) << 16);
}
__device__ __forceinline__ uint32_t packbf(float a, float b) {
    uint32_t lo = __bfloat16_as_ushort(__float2bfloat16(a));
    uint32_t hi = __bfloat16_as_ushort(__float2bfloat16(b));
    return lo | (hi << 16);
}

__device__ __forceinline__ void gload16(const void* g, void* l) {
    __builtin_amdgcn_global_load_lds(
        (const __attribute__((address_space(1))) uint32_t*)g,
        (__attribute__((address_space(3))) uint32_t*)l, 16, 0, 0);
}

struct Blk5 { const __hip_bfloat16* p[5]; };

// ------ edge pass 1: ONE packed 64-bit atomic = {cnt:16 | deg_fix:48} ------
__global__ __launch_bounds__(256) void edge_kernel(
    const int* __restrict__ ei, const float* __restrict__ coor,
    const float* __restrict__ theta, const int* __restrict__ mm,
    unsigned long long* __restrict__ packed, unsigned short* __restrict__ rank)
{
    int e = blockIdx.x * 256 + threadIdx.x;
    if (e >= NEDGE) return;
    float tom = theta[0] / (float)mm[0];
    int r = ei[e], c = ei[NEDGE + e];
    float2 pr = *(const float2*)(coor + 2*(size_t)r);
    float2 pc = *(const float2*)(coor + 2*(size_t)c);
    float dx = pr.x - pc.x, dy = pr.y - pc.y;
    float w = expf(-(dx*dx + dy*dy) * tom);
    unsigned long long enc = (1ULL << 48)
        | (unsigned long long)(unsigned int)__float2uint_rn(w * FIXSCALE);
    unsigned long long old = atomicAdd(&packed[r], enc);
    rank[e] = (unsigned short)(old >> 48);
}

// ---------------- 3-phase parallel scan (reads counts from packed) --------
__global__ __launch_bounds__(1024) void scan_local(
    const unsigned long long* __restrict__ packed, int* __restrict__ row_ptr,
    int* __restrict__ bsum, int n)
{
    __shared__ int wsum[16];
    int b = blockIdx.x, tid = threadIdx.x;
    int i = b * 1024 + tid;
    int lane = tid & 63, wv = tid >> 6;
    int v = (i < n) ? (int)(packed[i] >> 48) : 0;
    #pragma unroll
    for (int off = 1; off < 64; off <<= 1) {
        int t = __shfl_up(v, off, 64);
        if (lane >= off) v += t;
    }
    if (lane == 63) wsum[wv] = v;
    __syncthreads();
    if (tid < 16) {
        int t = wsum[tid];
        #pragma unroll
        for (int off = 1; off < 16; off <<= 1) {
            int u = __shfl_up(t, off, 64);
            if (tid >= off) t += u;
        }
        wsum[tid] = t;
    }
    __syncthreads();
    int incl = v + ((wv == 0) ? 0 : wsum[wv - 1]);
    if (i < n) row_ptr[i + 1] = incl;
    if (tid == 0) bsum[b] = wsum[15];
}

__global__ __launch_bounds__(128) void scan_carry(int* __restrict__ bsum, int n)
{
    __shared__ int ws[2];
    int tid = threadIdx.x, lane = tid & 63, wv = tid >> 6;
    int v = (tid < n) ? bsum[tid] : 0;
    int incl = v;
    #pragma unroll
    for (int off = 1; off < 64; off <<= 1) {
        int t = __shfl_up(incl, off, 64);
        if (lane >= off) incl += t;
    }
    if (lane == 63) ws[wv] = incl;
    __syncthreads();
    int excl = incl - v + ((wv == 0) ? 0 : ws[0]);
    if (tid < n) bsum[tid] = excl;
}

__global__ __launch_bounds__(256) void scan_add(
    const int* __restrict__ bsum, int* __restrict__ row_ptr, int n)
{
    int i = blockIdx.x * 256 + threadIdx.x;
    if (i == 0) row_ptr[0] = 0;
    if (i < n) row_ptr[i + 1] += bsum[i >> 10];
}

// ------ edge pass 2: ATOMIC-FREE fill; packed edge data {col, nrm} --------
__global__ __launch_bounds__(256) void fill_kernel(
    const int* __restrict__ ei, const float* __restrict__ coor,
    const float* __restrict__ theta, const int* __restrict__ mm,
    const unsigned long long* __restrict__ packed,
    const unsigned short* __restrict__ rank, const int* __restrict__ row_ptr,
    uint2* __restrict__ edat)
{
    int e = blockIdx.x * 256 + threadIdx.x;
    if (e >= NEDGE) return;
    float tom = theta[0] / (float)mm[0];
    int r = ei[e], c = ei[NEDGE + e];
    float2 pr = *(const float2*)(coor + 2*(size_t)r);
    float2 pc = *(const float2*)(coor + 2*(size_t)c);
    float dx = pr.x - pc.x, dy = pr.y - pc.y;
    float w = expf(-(dx*dx + dy*dy) * tom);
    float deg = (float)(double)(packed[r] & 0xFFFFFFFFFFFFULL) * (1.0f / FIXSCALE);
    int pos = row_ptr[r] + rank[e];
    uint2 d;
    d.x = (unsigned)c;
    d.y = __float_as_uint(w / (deg + DEG_EPS));
    edat[pos] = d;
}

// ---------------- cast feature -> bf16 slot ([N,128]) ----------------
__global__ __launch_bounds__(256) void cast_feat_kernel(
    const float* __restrict__ f, __hip_bfloat16* __restrict__ x0)
{
    int i = blockIdx.x * 256 + threadIdx.x;      // over N*64 float2 units
    int node = i >> 6, l2 = i & 63;
    if (node >= NNODES) return;
    float2 v = *(const float2*)(f + (size_t)node * DFEAT + l2 * 2);
    __hip_bfloat162 hb;
    hb.x = __float2bfloat16(v.x);
    hb.y = __float2bfloat16(v.y);
    *(__hip_bfloat162*)(x0 + (size_t)node * DFEAT + l2 * 2) = hb;
}

// ---------------- cast W1 -> bf16 ----------------
__global__ __launch_bounds__(256) void cast_w1_kernel(
    const float* __restrict__ w1, __hip_bfloat16* __restrict__ o)
{
    int i = blockIdx.x * 256 + threadIdx.x;
    if (i < HIDN * FAN1) o[i] = __float2bfloat16(w1[i]);
}

// ------- prop hop: wave/node; 4 quarter-lanes own edge streams, 16B/lane ---
__global__ __launch_bounds__(256) void prop_kernel(
    const __hip_bfloat16* __restrict__ x, __hip_bfloat16* __restrict__ y,
    const int* __restrict__ row_ptr, const uint2* __restrict__ edat)
{
    int gw = (blockIdx.x * 256 + threadIdx.x) >> 6;
    if (gw >= NNODES) return;
    int lane = threadIdx.x & 63;
    int q = lane >> 4, sl = lane & 15;
    int beg = row_ptr[gw], end = row_ptr[gw + 1];
    float a0 = 0.f, a1 = 0.f, a2 = 0.f, a3 = 0.f;
    float a4 = 0.f, a5 = 0.f, a6 = 0.f, a7 = 0.f;
    int e = beg + q;
    for (; e + 12 < end; e += 16) {   // this lane: e, e+4, e+8, e+12
        uint2 e0 = edat[e], e1 = edat[e + 4], e2 = edat[e + 8], e3 = edat[e + 12];
        float w0 = __uint_as_float(e0.y), w1 = __uint_as_float(e1.y);
        float w2 = __uint_as_float(e2.y), w3 = __uint_as_float(e3.y);
        uint4 u0 = *(const uint4*)(x + (size_t)e0.x * DFEAT + sl * 8);
        uint4 u1 = *(const uint4*)(x + (size_t)e1.x * DFEAT + sl * 8);
        uint4 u2 = *(const uint4*)(x + (size_t)e2.x * DFEAT + sl * 8);
        uint4 u3 = *(const uint4*)(x + (size_t)e3.x * DFEAT + sl * 8);
        a0 += w0 * bf16lo(u0.x); a1 += w0 * bf16hi(u0.x);
        a2 += w0 * bf16lo(u0.y); a3 += w0 * bf16hi(u0.y);
        a4 += w0 * bf16lo(u0.z); a5 += w0 * bf16hi(u0.z);
        a6 += w0 * bf16lo(u0.w); a7 += w0 * bf16hi(u0.w);
        a0 += w1 * bf16lo(u1.x); a1 += w1 * bf16hi(u1.x);
        a2 += w1 * bf16lo(u1.y); a3 += w1 * bf16hi(u1.y);
        a4 += w1 * bf16lo(u1.z); a5 += w1 * bf16hi(u1.z);
        a6 += w1 * bf16lo(u1.w); a7 += w1 * bf16hi(u1.w);
        a0 += w2 * bf16lo(u2.x); a1 += w2 * bf16hi(u2.x);
        a2 += w2 * bf16lo(u2.y); a3 += w2 * bf16hi(u2.y);
        a4 += w2 * bf16lo(u2.z); a5 += w2 * bf16hi(u2.z);
        a6 += w2 * bf16lo(u2.w); a7 += w2 * bf16hi(u2.w);
        a0 += w3 * bf16lo(u3.x); a1 += w3 * bf16hi(u3.x);
        a2 += w3 * bf16lo(u3.y); a3 += w3 * bf16hi(u3.y);
        a4 += w3 * bf16lo(u3.z); a5 += w3 * bf16hi(u3.z);
        a6 += w3 * bf16lo(u3.w); a7 += w3 * bf16hi(u3.w);
    }
    for (; e < end; e += 4) {
        uint2 e0 = edat[e];
        float w0 = __uint_as_float(e0.y);
        uint4 u0 = *(const uint4*)(x + (size_t)e0.x * DFEAT + sl * 8);
        a0 += w0 * bf16lo(u0.x); a1 += w0 * bf16hi(u0.x);
        a2 += w0 * bf16lo(u0.y); a3 += w0 * bf16hi(u0.y);
        a4 += w0 * bf16lo(u0.z); a5 += w0 * bf16hi(u0.z);
        a6 += w0 * bf16lo(u0.w); a7 += w0 * bf16hi(u0.w);
    }
    a0 += __shfl_xor(a0, 16, 64); a0 += __shfl_xor(a0, 32, 64);
    a1 += __shfl_xor(a1, 16, 64); a1 += __shfl_xor(a1, 32, 64);
    a2 += __shfl_xor(a2, 16, 64); a2 += __shfl_xor(a2, 32, 64);
    a3 += __shfl_xor(a3, 16, 64); a3 += __shfl_xor(a3, 32, 64);
    a4 += __shfl_xor(a4, 16, 64); a4 += __shfl_xor(a4, 32, 64);
    a5 += __shfl_xor(a5, 16, 64); a5 += __shfl_xor(a5, 32, 64);
    a6 += __shfl_xor(a6, 16, 64); a6 += __shfl_xor(a6, 32, 64);
    a7 += __shfl_xor(a7, 16, 64); a7 += __shfl_xor(a7, 32, 64);
    if (q == 0) {
        uint4 o;
        o.x = packbf(a0, a1);
        o.y = packbf(a2, a3);
        o.z = packbf(a4, a5);
        o.w = packbf(a6, a7);
        *(uint4*)(y + (size_t)gw * DFEAT + sl * 8) = o;
    }
}

// ---- fc1: 128x128 tile, BK=32, 3-buffer LDS ring, 2-DEEP stage-ahead
//      (vmcnt(8) leaves 2 K-steps in flight), h1 N-BLOCK-MAJOR streaming ----
// grid 3128 = 8 XCD chunks x 391; lid = (pid%8)*391 + pid/8; n-fast
// mode bit0 = RMW accumulate, bit1 = finalize (bias+lrelu+stats)
__global__ __launch_bounds__(256) void fc1_kernel(
    Blk5 blks, const __hip_bfloat16* __restrict__ w1,
    const float* __restrict__ b1, __hip_bfloat16* __restrict__ h1b,
    float* __restrict__ gsum, float* __restrict__ gsq,
    int nkt, int kb0, int mode)
{
    __shared__ char smem[49664];   // 3 x 16KB K-step bufs; epilogue: 32K tile + 512B stats
    int pid = blockIdx.x;
    int lid = (pid & 7) * 391 + (pid >> 3);   // XCD-chunked bijective remap
    int n0 = (lid & 3) * 128;
    int m0 = (lid >> 2) * 128;
    int tid = threadIdx.x, lane = tid & 63, wv = tid >> 6;
    int wr = wv >> 1, wc = wv & 1;

    f32x4 acc[4][4];
    #pragma unroll
    for (int i = 0; i < 4; ++i)
        #pragma unroll
        for (int j = 0; j < 4; ++j)
            acc[i][j] = (f32x4){0.f, 0.f, 0.f, 0.f};

// Linear staging: buffer hb at smem+hb*16384 (A 8K | B 8K); 4 loads/wave.
#define STAGE(hb, ktv) do {                                                   \
        const __hip_bfloat16* xp = blks.p[(ktv) >> 2];                        \
        int koff_ = ((ktv) & 3) * 32;                                         \
        int kglob_ = (kb0 + ((ktv) >> 2)) * 128 + koff_;                      \
        char* Ab_ = smem + (hb) * 16384;                                      \
        char* Bb_ = Ab_ + 8192;                                               \
        _Pragma("unroll")                                                     \
        for (int l = 0; l < 2; ++l) {                                         \
            int u = l * 256 + wv * 64 + lane;                                 \
            int row_ = u >> 2, qq_ = u & 3;                                   \
            gload16(xp + (size_t)(m0 + row_) * DFEAT + koff_ + qq_ * 8,       \
                    Ab_ + u * 16);                                            \
            gload16(w1 + (size_t)(n0 + row_) * FAN1 + kglob_ + qq_ * 8,       \
                    Bb_ + u * 16);                                            \
        }                                                                     \
    } while (0)

    STAGE(0, 0);
    STAGE(1, 1);
    int bufsel = 0;                           // buffer of kt (cycles 0,1,2)
    for (int kt = 0; kt < nkt; ++kt) {        // runtime bound: no unroll
        __builtin_amdgcn_s_barrier();          // all waves done reading buf[kt-1]
        if (kt + 2 < nkt) {
            int nb = bufsel + 2; if (nb >= 3) nb -= 3;
            STAGE(nb, kt + 2);                 // overwrites buf of kt-1
            asm volatile("s_waitcnt vmcnt(8)" ::: "memory");   // kt's 4 done
        } else if (kt + 1 < nkt) {
            asm volatile("s_waitcnt vmcnt(4)" ::: "memory");
        } else {
            asm volatile("s_waitcnt vmcnt(0)" ::: "memory");
        }
        __builtin_amdgcn_s_barrier();          // buf[kt] staged by all waves
        char* Ab = smem + bufsel * 16384;
        char* Bb = Ab + 8192;
        short8 af[4], bfr[4];
        #pragma unroll
        for (int i = 0; i < 4; ++i)
            af[i] = *(const short8*)(Ab + (wr * 64 + i * 16 + (lane & 15)) * 64 + (lane >> 4) * 16);
        #pragma unroll
        for (int j = 0; j < 4; ++j)
            bfr[j] = *(const short8*)(Bb + (wc * 64 + j * 16 + (lane & 15)) * 64 + (lane >> 4) * 16);
        #pragma unroll
        for (int j = 0; j < 4; ++j)
            #pragma unroll
            for (int i = 0; i < 4; ++i)
                acc[i][j] = __builtin_amdgcn_mfma_f32_16x16x32_bf16(af[i], bfr[j], acc[i][j], 0, 0, 0);
        ++bufsel; if (bufsel >= 3) bufsel -= 3;
    }
#undef STAGE

    // ---- epilogue: LDS transpose; STREAMING store to blocked h1 ----
    __syncthreads();
    __hip_bfloat16* tile = (__hip_bfloat16*)smem;      // [128][128] = 32KB
    float* lsum = (float*)(smem + 49152);              // [128]... 512B only
    float* lsq  = lsum + 64;
    // NOTE: need 128 floats for lsum + 128 for lsq = 1KB but only 512B left;
    // use tile tail region instead: place stats at smem+33792 (inside 48KB, after tile)
    lsum = (float*)(smem + 33792);
    lsq  = lsum + 128;
    bool fin = (mode & 2) != 0;
    if (fin && tid < 128) { lsum[tid] = 0.f; lsq[tid] = 0.f; }
    #pragma unroll
    for (int i = 0; i < 4; ++i) {
        #pragma unroll
        for (int j = 0; j < 4; ++j) {
            int col = wc * 64 + j * 16 + (lane & 15);
            #pragma unroll
            for (int r = 0; r < 4; ++r) {
                int row = wr * 64 + i * 16 + (lane >> 4) * 4 + r;
                tile[row * 128 + col] = __float2bfloat16(acc[i][j][r]);
            }
        }
    }
    __syncthreads();

    int cu = tid & 15, tr = tid >> 4;
    float bias[8];
    float s[8], q[8];
    #pragma unroll
    for (int e = 0; e < 8; ++e) { s[e] = 0.f; q[e] = 0.f; }
    if (fin) {
        #pragma unroll
        for (int e = 0; e < 8; ++e) bias[e] = b1[n0 + cu * 8 + e];
    }
    size_t blkbase = (size_t)(n0 >> 7) * NNODES * 128;
    for (int p = 0; p < 8; ++p) {
        int row = p * 16 + tr;
        int gm = m0 + row;
        if (gm >= NNODES) continue;
        short8 fresh = *(const short8*)(tile + row * 128 + cu * 8);
        size_t gidx = blkbase + (size_t)gm * 128 + cu * 8;   // streaming: 256B/row
        float v[8];
        #pragma unroll
        for (int e = 0; e < 8; ++e) v[e] = bf16s(fresh[e]);
        if (mode & 1) {
            short8 prev = *(const short8*)(h1b + gidx);
            #pragma unroll
            for (int e = 0; e < 8; ++e) v[e] += bf16s(prev[e]);
        }
        if (fin) {
            #pragma unroll
            for (int e = 0; e < 8; ++e) {
                float t = v[e] + bias[e];
                t = (t > 0.f) ? t : 0.2f * t;
                v[e] = t;
                s[e] += t;
                q[e] += t * t;
            }
        }
        short8 outv;
        #pragma unroll
        for (int e = 0; e < 8; ++e) outv[e] = (short)__bfloat16_as_ushort(__float2bfloat16(v[e]));
        *(short8*)(h1b + gidx) = outv;
    }
    if (fin) {
        #pragma unroll
        for (int e = 0; e < 8; ++e) {
            atomicAdd(&lsum[cu * 8 + e], s[e]);
            atomicAdd(&lsq[cu * 8 + e], q[e]);
        }
        __syncthreads();
        if (tid < 128) {
            atomicAdd(&gsum[n0 + tid], lsum[tid]);
            atomicAdd(&gsq[n0 + tid], lsq[tid]);
        }
    }
}

// ---------------- BN finalize: fold into W2 + const vector ----------------
__global__ __launch_bounds__(512) void bn_finalize(
    const float* __restrict__ gsum, const float* __restrict__ gsq,
    const float* __restrict__ gamma, const float* __restrict__ beta,
    const float* __restrict__ w2, const float* __restrict__ b2,
    __hip_bfloat16* __restrict__ w2s, float* __restrict__ cvec)
{
    __shared__ float ts[HIDN];
    int tid = threadIdx.x;              // 512 threads
    float mu = gsum[tid] * (1.0f / NNODES);
    float var = gsq[tid] * (1.0f / NNODES) - mu * mu;
    float s = gamma[tid] * rsqrtf(var + BN_EPS);
    float t = beta[tid] - mu * s;
    ts[tid] = t;
    for (int o = 0; o < OUTD; ++o)
        w2s[o * HIDN + tid] = __float2bfloat16(w2[o * HIDN + tid] * s);
    __syncthreads();
    int lane = tid & 63, wv = tid >> 6; // 8 waves
    for (int o = wv; o < OUTD; o += 8) {
        float p = 0.f;
        for (int j = lane; j < HIDN; j += 64) p += ts[j] * w2[o * HIDN + j];
        #pragma unroll
        for (int off = 32; off; off >>= 1) p += __shfl_xor(p, off, 64);
        if (lane == 0) cvec[o] = p + b2[o];
    }
}

// ---------------- fc2: blocked h1 [4][N][128] x W2^T -> out [N,32] ---------
__global__ __launch_bounds__(256) void fc2_kernel(
    const __hip_bfloat16* __restrict__ h1b, const __hip_bfloat16* __restrict__ w2s,
    const float* __restrict__ cvec, float* __restrict__ out)
{
    int gw = (blockIdx.x * 256 + threadIdx.x) >> 6;
    if (gw >= NNODES / 16) return;
    int lane = threadIdx.x & 63;
    int m0 = gw * 16;
    f32x4 acc[2];
    acc[0] = (f32x4){0.f, 0.f, 0.f, 0.f};
    acc[1] = (f32x4){0.f, 0.f, 0.f, 0.f};
    #pragma unroll
    for (int kt = 0; kt < HIDN / 32; ++kt) {
        int k0 = kt * 32;
        short8 a = *(const short8*)(h1b
            + ((size_t)(kt >> 2) * NNODES + (m0 + (lane & 15))) * 128
            + (kt & 3) * 32 + (lane >> 4) * 8);
        #pragma unroll
        for (int j = 0; j < 2; ++j) {
            short8 b = *(const short8*)(w2s + (size_t)(j * 16 + (lane & 15)) * HIDN + k0 + (lane >> 4) * 8);
            acc[j] = __builtin_amdgcn_mfma_f32_16x16x32_bf16(a, b, acc[j], 0, 0, 0);
        }
    }
    #pragma unroll
    for (int j = 0; j < 2; ++j) {
        int col = j * 16 + (lane & 15);
        float cadd = cvec[col];
        #pragma unroll
        for (int r = 0; r < 4; ++r) {
            int row = m0 + (lane >> 4) * 4 + r;
            out[(size_t)row * OUTD + col] = acc[j][r] + cadd;
        }
    }
}

// ---------------- host ----------------
struct Ptrs {
    float *gsum, *gsq, *cvec;
    int *row_ptr, *bsum;
    unsigned long long* packed;
    unsigned short* rank;
    uint2* edat;
    __hip_bfloat16 *slot[5], *h1acc, *w1b, *w2s;
};

static size_t layout(char* base, int nslots, Ptrs& P) {
    char* p = base;
    auto take = [&](size_t b) {
        char* q = (char*)(((uintptr_t)p + 255) & ~(uintptr_t)255);
        p = q + b;
        return q;
    };
    P.packed  = (unsigned long long*)take((size_t)NNODES * 8);
    P.rank    = (unsigned short*)take((size_t)NEDGE * 2);
    P.row_ptr = (int*)  take((size_t)(NNODES + 1) * 4);
    P.bsum    = (int*)  take(128 * 4);
    P.edat    = (uint2*)take((size_t)NEDGE * 8);
    P.h1acc   = (__hip_bfloat16*)take((size_t)NNODES * HIDN * 2 + 65536);
    P.w1b     = (__hip_bfloat16*)take((size_t)HIDN * FAN1 * 2);
    P.w2s     = (__hip_bfloat16*)take((size_t)OUTD * HIDN * 2);
    P.gsum    = (float*)take(HIDN * 4);
    P.gsq     = (float*)take(HIDN * 4);
    P.cvec    = (float*)take(OUTD * 4);
    for (int i = 0; i < 5; ++i) P.slot[i] = nullptr;
    for (int i = 0; i < nslots; ++i)   // +32KB pad: fc1 A-stage overreads last m-tile
        P.slot[i] = (__hip_bfloat16*)take((size_t)NNODES * DFEAT * 2 + 32768);
    return (size_t)(p - base);
}

extern "C" void kernel_launch(void* const* d_in, const int* in_sizes, int n_in,
                              void* d_out, int out_size, void* d_ws, size_t ws_size,
                              hipStream_t stream)
{
    const float* feature = (const float*)d_in[0];
    const float* coor    = (const float*)d_in[1];
    const float* theta   = (const float*)d_in[2];
    const float* W1      = (const float*)d_in[3];
    const float* b1      = (const float*)d_in[4];
    const float* gamma   = (const float*)d_in[5];
    const float* beta    = (const float*)d_in[6];
    const float* W2      = (const float*)d_in[7];
    const float* b2      = (const float*)d_in[8];
    const int*   ei      = (const int*)d_in[9];
    const int*   mm      = (const int*)d_in[10];
    float* out = (float*)d_out;
    (void)in_sizes; (void)n_in; (void)out_size;

    Ptrs P;
    size_t need5 = layout((char*)0, 5, P);
    int nslots = (ws_size >= need5) ? 5 : 3;
    layout((char*)d_ws, nslots, P);

    hipMemsetAsync(P.packed, 0, (size_t)NNODES * 8, stream);
    hipMemsetAsync(P.gsum,   0, HIDN * 4, stream);
    hipMemsetAsync(P.gsq,    0, HIDN * 4, stream);

    int eb = (NEDGE + 255) / 256;
    int nchunk = (NNODES + 1023) / 1024;
    edge_kernel<<<eb, 256, 0, stream>>>(ei, coor, theta, mm, P.packed, P.rank);
    scan_local<<<nchunk, 1024, 0, stream>>>(P.packed, P.row_ptr, P.bsum, NNODES);
    scan_carry<<<1, 128, 0, stream>>>(P.bsum, nchunk);
    scan_add<<<(NNODES + 255) / 256, 256, 0, stream>>>(P.bsum, P.row_ptr, NNODES);
    fill_kernel<<<eb, 256, 0, stream>>>(ei, coor, theta, mm, P.packed, P.rank,
                                        P.row_ptr, P.edat);

    cast_w1_kernel<<<(HIDN * FAN1 + 255) / 256, 256, 0, stream>>>(W1, P.w1b);
    cast_feat_kernel<<<(NNODES * 64) / 256, 256, 0, stream>>>(feature, P.slot[0]);

    int pb = (NNODES * 64) / 256;
    int fgrid = 8 * 391;      // 3128 blocks, XCD-chunk swizzled in-kernel

    auto launch_fc1 = [&](int nblk, int kb0, int mode) {
        Blk5 b;
        for (int i = 0; i < 5; ++i) b.p[i] = P.slot[0];
        for (int i = 0; i < nblk; ++i) b.p[i] = P.slot[i];
        fc1_kernel<<<fgrid, 256, 0, stream>>>(b, P.w1b, b1, P.h1acc,
                                              P.gsum, P.gsq, nblk * 4, kb0, mode);
    };

    if (nslots == 5) {
        // blocks 0..4 -> slots 0..4 ; blocks 5..8 -> slots 0..3
        for (int k = 1; k <= KHOP; ++k) {
            prop_kernel<<<pb, 256, 0, stream>>>(P.slot[(k - 1) % 5],
                                                P.slot[k % 5],
                                                P.row_ptr, P.edat);
            if (k == 4) launch_fc1(5, 0, 0);
        }
        launch_fc1(4, 5, 3);
    } else {
        // blocks 0..8 rotate through slots 0,1,2
        for (int k = 1; k <= KHOP; ++k) {
            prop_kernel<<<pb, 256, 0, stream>>>(P.slot[(k - 1) % 3],
                                                P.slot[k % 3],
                                                P.row_ptr, P.edat);
            if (k == 2) launch_fc1(3, 0, 0);
            if (k == 5) launch_fc1(3, 3, 1);
        }
        launch_fc1(3, 6, 3);
    }

    bn_finalize<<<1, 512, 0, stream>>>(P.gsum, P.gsq, gamma, beta, W2, b2,
                                       P.w2s, P.cvec);
    fc2_kernel<<<(NNODES / 16 * 64 + 255) / 256, 256, 0, stream>>>(P.h1acc, P.w2s,
                                                                   P.cvec, out);
}

// Round 15
// 902.971 us; speedup vs baseline: 1.0832x; 1.0015x over previous
//
#include <hip/hip_runtime.h>
#include <hip/hip_bf16.h>
#include <cstdint>
#include <cstddef>

#define NNODES 100000
#define DFEAT 128
#define KHOP 8
#define FAN1 1152        // D*(K+1)
#define HIDN 512
#define OUTD 32
#define NEDGE 1600000
#define BN_EPS 1e-5f
#define DEG_EPS 1e-8f
#define FIXSCALE 67108864.0f   // 2^26

using short8 = __attribute__((ext_vector_type(8))) short;
using f32x4  = __attribute__((ext_vector_type(4))) float;

__device__ __forceinline__ float bf16lo(uint32_t u) { return __uint_as_float(u << 16); }
__device__ __forceinline__ float bf16hi(uint32_t u) { return __uint_as_float(u & 0xffff0000u); }
__device__ __forceinline__ float bf16s(short x) {
    return __uint_as_float(((uint32_t)(uint16_t)x) << 16);
}
__device__ __forceinline__ uint32_t packbf(float a, float b) {
    uint32_t lo = __bfloat16_as_ushort(__float2bfloat16(a));
    uint32_t hi = __bfloat16_as_ushort(__float2bfloat16(b));
    return lo | (hi << 16);
}

__device__ __forceinline__ void gload16(const void* g, void* l) {
    __builtin_amdgcn_global_load_lds(
        (const __attribute__((address_space(1))) uint32_t*)g,
        (__attribute__((address_space(3))) uint32_t*)l, 16, 0, 0);
}

struct Blk5 { const __hip_bfloat16* p[5]; };

// ------ edge pass 1: ONE packed 64-bit atomic = {cnt:16 | deg_fix:48} ------
__global__ __launch_bounds__(256) void edge_kernel(
    const int* __restrict__ ei, const float* __restrict__ coor,
    const float* __restrict__ theta, const int* __restrict__ mm,
    unsigned long long* __restrict__ packed, unsigned short* __restrict__ rank)
{
    int e = blockIdx.x * 256 + threadIdx.x;
    if (e >= NEDGE) return;
    float tom = theta[0] / (float)mm[0];
    int r = ei[e], c = ei[NEDGE + e];
    float2 pr = *(const float2*)(coor + 2*(size_t)r);
    float2 pc = *(const float2*)(coor + 2*(size_t)c);
    float dx = pr.x - pc.x, dy = pr.y - pc.y;
    float w = expf(-(dx*dx + dy*dy) * tom);
    unsigned long long enc = (1ULL << 48)
        | (unsigned long long)(unsigned int)__float2uint_rn(w * FIXSCALE);
    unsigned long long old = atomicAdd(&packed[r], enc);
    rank[e] = (unsigned short)(old >> 48);
}

// ---------------- 3-phase parallel scan (reads counts from packed) --------
__global__ __launch_bounds__(1024) void scan_local(
    const unsigned long long* __restrict__ packed, int* __restrict__ row_ptr,
    int* __restrict__ bsum, int n)
{
    __shared__ int wsum[16];
    int b = blockIdx.x, tid = threadIdx.x;
    int i = b * 1024 + tid;
    int lane = tid & 63, wv = tid >> 6;
    int v = (i < n) ? (int)(packed[i] >> 48) : 0;
    #pragma unroll
    for (int off = 1; off < 64; off <<= 1) {
        int t = __shfl_up(v, off, 64);
        if (lane >= off) v += t;
    }
    if (lane == 63) wsum[wv] = v;
    __syncthreads();
    if (tid < 16) {
        int t = wsum[tid];
        #pragma unroll
        for (int off = 1; off < 16; off <<= 1) {
            int u = __shfl_up(t, off, 64);
            if (tid >= off) t += u;
        }
        wsum[tid] = t;
    }
    __syncthreads();
    int incl = v + ((wv == 0) ? 0 : wsum[wv - 1]);
    if (i < n) row_ptr[i + 1] = incl;
    if (tid == 0) bsum[b] = wsum[15];
}

__global__ __launch_bounds__(128) void scan_carry(int* __restrict__ bsum, int n)
{
    __shared__ int ws[2];
    int tid = threadIdx.x, lane = tid & 63, wv = tid >> 6;
    int v = (tid < n) ? bsum[tid] : 0;
    int incl = v;
    #pragma unroll
    for (int off = 1; off < 64; off <<= 1) {
        int t = __shfl_up(incl, off, 64);
        if (lane >= off) incl += t;
    }
    if (lane == 63) ws[wv] = incl;
    __syncthreads();
    int excl = incl - v + ((wv == 0) ? 0 : ws[0]);
    if (tid < n) bsum[tid] = excl;
}

__global__ __launch_bounds__(256) void scan_add(
    const int* __restrict__ bsum, int* __restrict__ row_ptr, int n)
{
    int i = blockIdx.x * 256 + threadIdx.x;
    if (i == 0) row_ptr[0] = 0;
    if (i < n) row_ptr[i + 1] += bsum[i >> 10];
}

// ------ edge pass 2: ATOMIC-FREE fill; packed edge data {col, nrm} --------
__global__ __launch_bounds__(256) void fill_kernel(
    const int* __restrict__ ei, const float* __restrict__ coor,
    const float* __restrict__ theta, const int* __restrict__ mm,
    const unsigned long long* __restrict__ packed,
    const unsigned short* __restrict__ rank, const int* __restrict__ row_ptr,
    uint2* __restrict__ edat)
{
    int e = blockIdx.x * 256 + threadIdx.x;
    if (e >= NEDGE) return;
    float tom = theta[0] / (float)mm[0];
    int r = ei[e], c = ei[NEDGE + e];
    float2 pr = *(const float2*)(coor + 2*(size_t)r);
    float2 pc = *(const float2*)(coor + 2*(size_t)c);
    float dx = pr.x - pc.x, dy = pr.y - pc.y;
    float w = expf(-(dx*dx + dy*dy) * tom);
    float deg = (float)(double)(packed[r] & 0xFFFFFFFFFFFFULL) * (1.0f / FIXSCALE);
    int pos = row_ptr[r] + rank[e];
    uint2 d;
    d.x = (unsigned)c;
    d.y = __float_as_uint(w / (deg + DEG_EPS));
    edat[pos] = d;
}

// ---------------- cast feature -> bf16 slot ([N,128]) ----------------
__global__ __launch_bounds__(256) void cast_feat_kernel(
    const float* __restrict__ f, __hip_bfloat16* __restrict__ x0)
{
    int i = blockIdx.x * 256 + threadIdx.x;      // over N*64 float2 units
    int node = i >> 6, l2 = i & 63;
    if (node >= NNODES) return;
    float2 v = *(const float2*)(f + (size_t)node * DFEAT + l2 * 2);
    __hip_bfloat162 hb;
    hb.x = __float2bfloat16(v.x);
    hb.y = __float2bfloat16(v.y);
    *(__hip_bfloat162*)(x0 + (size_t)node * DFEAT + l2 * 2) = hb;
}

// ---------------- cast W1 -> bf16 ----------------
__global__ __launch_bounds__(256) void cast_w1_kernel(
    const float* __restrict__ w1, __hip_bfloat16* __restrict__ o)
{
    int i = blockIdx.x * 256 + threadIdx.x;
    if (i < HIDN * FAN1) o[i] = __float2bfloat16(w1[i]);
}

// ------- prop hop: wave/node; 4 quarter-lanes own edge streams, 16B/lane ---
__global__ __launch_bounds__(256) void prop_kernel(
    const __hip_bfloat16* __restrict__ x, __hip_bfloat16* __restrict__ y,
    const int* __restrict__ row_ptr, const uint2* __restrict__ edat)
{
    int gw = (blockIdx.x * 256 + threadIdx.x) >> 6;
    if (gw >= NNODES) return;
    int lane = threadIdx.x & 63;
    int q = lane >> 4, sl = lane & 15;
    int beg = row_ptr[gw], end = row_ptr[gw + 1];
    float a0 = 0.f, a1 = 0.f, a2 = 0.f, a3 = 0.f;
    float a4 = 0.f, a5 = 0.f, a6 = 0.f, a7 = 0.f;
    int e = beg + q;
    for (; e + 12 < end; e += 16) {   // this lane: e, e+4, e+8, e+12
        uint2 e0 = edat[e], e1 = edat[e + 4], e2 = edat[e + 8], e3 = edat[e + 12];
        float w0 = __uint_as_float(e0.y), w1 = __uint_as_float(e1.y);
        float w2 = __uint_as_float(e2.y), w3 = __uint_as_float(e3.y);
        uint4 u0 = *(const uint4*)(x + (size_t)e0.x * DFEAT + sl * 8);
        uint4 u1 = *(const uint4*)(x + (size_t)e1.x * DFEAT + sl * 8);
        uint4 u2 = *(const uint4*)(x + (size_t)e2.x * DFEAT + sl * 8);
        uint4 u3 = *(const uint4*)(x + (size_t)e3.x * DFEAT + sl * 8);
        a0 += w0 * bf16lo(u0.x); a1 += w0 * bf16hi(u0.x);
        a2 += w0 * bf16lo(u0.y); a3 += w0 * bf16hi(u0.y);
        a4 += w0 * bf16lo(u0.z); a5 += w0 * bf16hi(u0.z);
        a6 += w0 * bf16lo(u0.w); a7 += w0 * bf16hi(u0.w);
        a0 += w1 * bf16lo(u1.x); a1 += w1 * bf16hi(u1.x);
        a2 += w1 * bf16lo(u1.y); a3 += w1 * bf16hi(u1.y);
        a4 += w1 * bf16lo(u1.z); a5 += w1 * bf16hi(u1.z);
        a6 += w1 * bf16lo(u1.w); a7 += w1 * bf16hi(u1.w);
        a0 += w2 * bf16lo(u2.x); a1 += w2 * bf16hi(u2.x);
        a2 += w2 * bf16lo(u2.y); a3 += w2 * bf16hi(u2.y);
        a4 += w2 * bf16lo(u2.z); a5 += w2 * bf16hi(u2.z);
        a6 += w2 * bf16lo(u2.w); a7 += w2 * bf16hi(u2.w);
        a0 += w3 * bf16lo(u3.x); a1 += w3 * bf16hi(u3.x);
        a2 += w3 * bf16lo(u3.y); a3 += w3 * bf16hi(u3.y);
        a4 += w3 * bf16lo(u3.z); a5 += w3 * bf16hi(u3.z);
        a6 += w3 * bf16lo(u3.w); a7 += w3 * bf16hi(u3.w);
    }
    for (; e < end; e += 4) {
        uint2 e0 = edat[e];
        float w0 = __uint_as_float(e0.y);
        uint4 u0 = *(const uint4*)(x + (size_t)e0.x * DFEAT + sl * 8);
        a0 += w0 * bf16lo(u0.x); a1 += w0 * bf16hi(u0.x);
        a2 += w0 * bf16lo(u0.y); a3 += w0 * bf16hi(u0.y);
        a4 += w0 * bf16lo(u0.z); a5 += w0 * bf16hi(u0.z);
        a6 += w0 * bf16lo(u0.w); a7 += w0 * bf16hi(u0.w);
    }
    a0 += __shfl_xor(a0, 16, 64); a0 += __shfl_xor(a0, 32, 64);
    a1 += __shfl_xor(a1, 16, 64); a1 += __shfl_xor(a1, 32, 64);
    a2 += __shfl_xor(a2, 16, 64); a2 += __shfl_xor(a2, 32, 64);
    a3 += __shfl_xor(a3, 16, 64); a3 += __shfl_xor(a3, 32, 64);
    a4 += __shfl_xor(a4, 16, 64); a4 += __shfl_xor(a4, 32, 64);
    a5 += __shfl_xor(a5, 16, 64); a5 += __shfl_xor(a5, 32, 64);
    a6 += __shfl_xor(a6, 16, 64); a6 += __shfl_xor(a6, 32, 64);
    a7 += __shfl_xor(a7, 16, 64); a7 += __shfl_xor(a7, 32, 64);
    if (q == 0) {
        uint4 o;
        o.x = packbf(a0, a1);
        o.y = packbf(a2, a3);
        o.z = packbf(a4, a5);
        o.w = packbf(a6, a7);
        *(uint4*)(y + (size_t)gw * DFEAT + sl * 8) = o;
    }
}

// ---- fc1: r12-proven core (128x128, BK=32, linear LDS dbuf, vmcnt(4)),
//      h1 N-BLOCK-MAJOR [4][N][128] streaming epilogue ----
// grid 3128 = 8 XCD chunks x 391; lid = (pid%8)*391 + pid/8; n-fast
// mode bit0 = RMW accumulate, bit1 = finalize (bias+lrelu+stats)
__global__ __launch_bounds__(256) void fc1_kernel(
    Blk5 blks, const __hip_bfloat16* __restrict__ w1,
    const float* __restrict__ b1, __hip_bfloat16* __restrict__ h1b,
    float* __restrict__ gsum, float* __restrict__ gsq,
    int nkt, int kb0, int mode)
{
    __shared__ char smem[33792];   // dbuf: 2 x (A 8K | B 8K); epilogue: 32K tile + 1K stats
    int pid = blockIdx.x;
    int lid = (pid & 7) * 391 + (pid >> 3);   // XCD-chunked bijective remap
    int n0 = (lid & 3) * 128;
    int m0 = (lid >> 2) * 128;
    int tid = threadIdx.x, lane = tid & 63, wv = tid >> 6;
    int wr = wv >> 1, wc = wv & 1;

    f32x4 acc[4][4];
    #pragma unroll
    for (int i = 0; i < 4; ++i)
        #pragma unroll
        for (int j = 0; j < 4; ++j)
            acc[i][j] = (f32x4){0.f, 0.f, 0.f, 0.f};

#define STAGE(hb, ktv) do {                                                   \
        const __hip_bfloat16* xp = blks.p[(ktv) >> 2];                        \
        int koff_ = ((ktv) & 3) * 32;                                         \
        int kglob_ = (kb0 + ((ktv) >> 2)) * 128 + koff_;                      \
        char* Ab_ = smem + (hb) * 16384;                                      \
        char* Bb_ = Ab_ + 8192;                                               \
        _Pragma("unroll")                                                     \
        for (int l = 0; l < 2; ++l) {                                         \
            int u = l * 256 + wv * 64 + lane;                                 \
            int row_ = u >> 2, qq_ = u & 3;                                   \
            gload16(xp + (size_t)(m0 + row_) * DFEAT + koff_ + qq_ * 8,       \
                    Ab_ + u * 16);                                            \
            gload16(w1 + (size_t)(n0 + row_) * FAN1 + kglob_ + qq_ * 8,       \
                    Bb_ + u * 16);                                            \
        }                                                                     \
    } while (0)

    STAGE(0, 0);
    for (int kt = 0; kt < nkt; ++kt) {        // runtime bound: no unroll
        int cur = kt & 1;
        __builtin_amdgcn_s_barrier();          // prev compute done; buf^1 free
        if (kt + 1 < nkt) {
            STAGE(cur ^ 1, kt + 1);
            asm volatile("s_waitcnt vmcnt(4)" ::: "memory");   // cur's 4 done
        } else {
            asm volatile("s_waitcnt vmcnt(0)" ::: "memory");
        }
        __builtin_amdgcn_s_barrier();          // buf[cur] staged for all waves
        char* Ab = smem + cur * 16384;
        char* Bb = Ab + 8192;
        short8 af[4], bfr[4];
        #pragma unroll
        for (int i = 0; i < 4; ++i)
            af[i] = *(const short8*)(Ab + (wr * 64 + i * 16 + (lane & 15)) * 64 + (lane >> 4) * 16);
        #pragma unroll
        for (int j = 0; j < 4; ++j)
            bfr[j] = *(const short8*)(Bb + (wc * 64 + j * 16 + (lane & 15)) * 64 + (lane >> 4) * 16);
        #pragma unroll
        for (int j = 0; j < 4; ++j)
            #pragma unroll
            for (int i = 0; i < 4; ++i)
                acc[i][j] = __builtin_amdgcn_mfma_f32_16x16x32_bf16(af[i], bfr[j], acc[i][j], 0, 0, 0);
    }
#undef STAGE

    // ---- epilogue: LDS transpose; STREAMING store to blocked h1 ----
    __syncthreads();
    __hip_bfloat16* tile = (__hip_bfloat16*)smem;      // [128][128]
    float* lsum = (float*)(smem + 32768);              // [128]
    float* lsq  = lsum + 128;
    bool fin = (mode & 2) != 0;
    if (fin && tid < 128) { lsum[tid] = 0.f; lsq[tid] = 0.f; }
    #pragma unroll
    for (int i = 0; i < 4; ++i) {
        #pragma unroll
        for (int j = 0; j < 4; ++j) {
            int col = wc * 64 + j * 16 + (lane & 15);
            #pragma unroll
            for (int r = 0; r < 4; ++r) {
                int row = wr * 64 + i * 16 + (lane >> 4) * 4 + r;
                tile[row * 128 + col] = __float2bfloat16(acc[i][j][r]);
            }
        }
    }
    __syncthreads();

    int cu = tid & 15, tr = tid >> 4;
    float bias[8];
    float s[8], q[8];
    #pragma unroll
    for (int e = 0; e < 8; ++e) { s[e] = 0.f; q[e] = 0.f; }
    if (fin) {
        #pragma unroll
        for (int e = 0; e < 8; ++e) bias[e] = b1[n0 + cu * 8 + e];
    }
    size_t blkbase = (size_t)(n0 >> 7) * NNODES * 128;
    for (int p = 0; p < 8; ++p) {
        int row = p * 16 + tr;
        int gm = m0 + row;
        if (gm >= NNODES) continue;
        short8 fresh = *(const short8*)(tile + row * 128 + cu * 8);
        size_t gidx = blkbase + (size_t)gm * 128 + cu * 8;   // streaming: 256B/row
        float v[8];
        #pragma unroll
        for (int e = 0; e < 8; ++e) v[e] = bf16s(fresh[e]);
        if (mode & 1) {
            short8 prev = *(const short8*)(h1b + gidx);
            #pragma unroll
            for (int e = 0; e < 8; ++e) v[e] += bf16s(prev[e]);
        }
        if (fin) {
            #pragma unroll
            for (int e = 0; e < 8; ++e) {
                float t = v[e] + bias[e];
                t = (t > 0.f) ? t : 0.2f * t;
                v[e] = t;
                s[e] += t;
                q[e] += t * t;
            }
        }
        short8 outv;
        #pragma unroll
        for (int e = 0; e < 8; ++e) outv[e] = (short)__bfloat16_as_ushort(__float2bfloat16(v[e]));
        *(short8*)(h1b + gidx) = outv;
    }
    if (fin) {
        #pragma unroll
        for (int e = 0; e < 8; ++e) {
            atomicAdd(&lsum[cu * 8 + e], s[e]);
            atomicAdd(&lsq[cu * 8 + e], q[e]);
        }
        __syncthreads();
        if (tid < 128) {
            atomicAdd(&gsum[n0 + tid], lsum[tid]);
            atomicAdd(&gsq[n0 + tid], lsq[tid]);
        }
    }
}

// ---------------- BN finalize: fold into W2 + const vector ----------------
__global__ __launch_bounds__(512) void bn_finalize(
    const float* __restrict__ gsum, const float* __restrict__ gsq,
    const float* __restrict__ gamma, const float* __restrict__ beta,
    const float* __restrict__ w2, const float* __restrict__ b2,
    __hip_bfloat16* __restrict__ w2s, float* __restrict__ cvec)
{
    __shared__ float ts[HIDN];
    int tid = threadIdx.x;              // 512 threads
    float mu = gsum[tid] * (1.0f / NNODES);
    float var = gsq[tid] * (1.0f / NNODES) - mu * mu;
    float s = gamma[tid] * rsqrtf(var + BN_EPS);
    float t = beta[tid] - mu * s;
    ts[tid] = t;
    for (int o = 0; o < OUTD; ++o)
        w2s[o * HIDN + tid] = __float2bfloat16(w2[o * HIDN + tid] * s);
    __syncthreads();
    int lane = tid & 63, wv = tid >> 6; // 8 waves
    for (int o = wv; o < OUTD; o += 8) {
        float p = 0.f;
        for (int j = lane; j < HIDN; j += 64) p += ts[j] * w2[o * HIDN + j];
        #pragma unroll
        for (int off = 32; off; off >>= 1) p += __shfl_xor(p, off, 64);
        if (lane == 0) cvec[o] = p + b2[o];
    }
}

// ---------------- fc2: blocked h1 [4][N][128] x W2^T -> out [N,32] ---------
__global__ __launch_bounds__(256) void fc2_kernel(
    const __hip_bfloat16* __restrict__ h1b, const __hip_bfloat16* __restrict__ w2s,
    const float* __restrict__ cvec, float* __restrict__ out)
{
    int gw = (blockIdx.x * 256 + threadIdx.x) >> 6;
    if (gw >= NNODES / 16) return;
    int lane = threadIdx.x & 63;
    int m0 = gw * 16;
    f32x4 acc[2];
    acc[0] = (f32x4){0.f, 0.f, 0.f, 0.f};
    acc[1] = (f32x4){0.f, 0.f, 0.f, 0.f};
    #pragma unroll
    for (int kt = 0; kt < HIDN / 32; ++kt) {
        int k0 = kt * 32;
        short8 a = *(const short8*)(h1b
            + ((size_t)(kt >> 2) * NNODES + (m0 + (lane & 15))) * 128
            + (kt & 3) * 32 + (lane >> 4) * 8);
        #pragma unroll
        for (int j = 0; j < 2; ++j) {
            short8 b = *(const short8*)(w2s + (size_t)(j * 16 + (lane & 15)) * HIDN + k0 + (lane >> 4) * 8);
            acc[j] = __builtin_amdgcn_mfma_f32_16x16x32_bf16(a, b, acc[j], 0, 0, 0);
        }
    }
    #pragma unroll
    for (int j = 0; j < 2; ++j) {
        int col = j * 16 + (lane & 15);
        float cadd = cvec[col];
        #pragma unroll
        for (int r = 0; r < 4; ++r) {
            int row = m0 + (lane >> 4) * 4 + r;
            out[(size_t)row * OUTD + col] = acc[j][r] + cadd;
        }
    }
}

// ---------------- host ----------------
struct Ptrs {
    float *gsum, *gsq, *cvec;
    int *row_ptr, *bsum;
    unsigned long long* packed;
    unsigned short* rank;
    uint2* edat;
    __hip_bfloat16 *slot[5], *h1acc, *w1b, *w2s;
};

// rank/packed/bsum are dead before h1acc's first write (fill+scan precede
// fc1 launch 1, which fully overwrites h1acc) -> carve them from h1acc front.
static size_t layout(char* base, int nslots, Ptrs& P) {
    char* p = base;
    auto take = [&](size_t b) {
        char* q = (char*)(((uintptr_t)p + 255) & ~(uintptr_t)255);
        p = q + b;
        return q;
    };
    P.h1acc   = (__hip_bfloat16*)take((size_t)NNODES * HIDN * 2);
    {   // aliased scratch inside h1acc
        char* a = (char*)P.h1acc;
        P.rank   = (unsigned short*)a;                  a += (size_t)NEDGE * 2;
        a = (char*)(((uintptr_t)a + 255) & ~(uintptr_t)255);
        P.packed = (unsigned long long*)a;              a += (size_t)NNODES * 8;
        a = (char*)(((uintptr_t)a + 255) & ~(uintptr_t)255);
        P.bsum   = (int*)a;
    }
    P.row_ptr = (int*)  take((size_t)(NNODES + 1) * 4);
    P.edat    = (uint2*)take((size_t)NEDGE * 8);
    P.w1b     = (__hip_bfloat16*)take((size_t)HIDN * FAN1 * 2);
    P.w2s     = (__hip_bfloat16*)take((size_t)OUTD * HIDN * 2);
    P.gsum    = (float*)take(HIDN * 4);
    P.gsq     = (float*)take(HIDN * 4);
    P.cvec    = (float*)take(OUTD * 4);
    for (int i = 0; i < 5; ++i) P.slot[i] = nullptr;
    for (int i = 0; i < nslots; ++i)   // +32KB pad: fc1 A-stage overreads last m-tile
        P.slot[i] = (__hip_bfloat16*)take((size_t)NNODES * DFEAT * 2 + 32768);
    return (size_t)(p - base);
}

extern "C" void kernel_launch(void* const* d_in, const int* in_sizes, int n_in,
                              void* d_out, int out_size, void* d_ws, size_t ws_size,
                              hipStream_t stream)
{
    const float* feature = (const float*)d_in[0];
    const float* coor    = (const float*)d_in[1];
    const float* theta   = (const float*)d_in[2];
    const float* W1      = (const float*)d_in[3];
    const float* b1      = (const float*)d_in[4];
    const float* gamma   = (const float*)d_in[5];
    const float* beta    = (const float*)d_in[6];
    const float* W2      = (const float*)d_in[7];
    const float* b2      = (const float*)d_in[8];
    const int*   ei      = (const int*)d_in[9];
    const int*   mm      = (const int*)d_in[10];
    float* out = (float*)d_out;
    (void)in_sizes; (void)n_in; (void)out_size;

    Ptrs P;
    size_t need5 = layout((char*)0, 5, P);
    int nslots = (ws_size >= need5) ? 5 : 3;
    layout((char*)d_ws, nslots, P);

    hipMemsetAsync(P.packed, 0, (size_t)NNODES * 8, stream);
    hipMemsetAsync(P.gsum,   0, HIDN * 4, stream);
    hipMemsetAsync(P.gsq,    0, HIDN * 4, stream);

    int eb = (NEDGE + 255) / 256;
    int nchunk = (NNODES + 1023) / 1024;
    edge_kernel<<<eb, 256, 0, stream>>>(ei, coor, theta, mm, P.packed, P.rank);
    scan_local<<<nchunk, 1024, 0, stream>>>(P.packed, P.row_ptr, P.bsum, NNODES);
    scan_carry<<<1, 128, 0, stream>>>(P.bsum, nchunk);
    scan_add<<<(NNODES + 255) / 256, 256, 0, stream>>>(P.bsum, P.row_ptr, NNODES);
    fill_kernel<<<eb, 256, 0, stream>>>(ei, coor, theta, mm, P.packed, P.rank,
                                        P.row_ptr, P.edat);

    cast_w1_kernel<<<(HIDN * FAN1 + 255) / 256, 256, 0, stream>>>(W1, P.w1b);
    cast_feat_kernel<<<(NNODES * 64) / 256, 256, 0, stream>>>(feature, P.slot[0]);

    int pb = (NNODES * 64) / 256;
    int fgrid = 8 * 391;      // 3128 blocks, XCD-chunk swizzled in-kernel

    auto launch_fc1 = [&](int first_slot, int nblk, int kb0, int mode) {
        Blk5 b;
        for (int i = 0; i < 5; ++i) b.p[i] = P.slot[0];
        for (int i = 0; i < nblk; ++i) b.p[i] = P.slot[(first_slot + i) % nslots];
        fc1_kernel<<<fgrid, 256, 0, stream>>>(b, P.w1b, b1, P.h1acc,
                                              P.gsum, P.gsq, nblk * 4, kb0, mode);
    };

    if (nslots == 5) {
        // blocks 0..4 -> slots 0..4 (after hop 4); blocks 5..8 -> slots 0..3
        for (int k = 1; k <= KHOP; ++k) {
            prop_kernel<<<pb, 256, 0, stream>>>(P.slot[(k - 1) % 5],
                                                P.slot[k % 5],
                                                P.row_ptr, P.edat);
            if (k == 4) launch_fc1(0, 5, 0, 0);
        }
        launch_fc1(0, 4, 5, 3);
    } else {
        // blocks 0..8 rotate through slots 0,1,2
        for (int k = 1; k <= KHOP; ++k) {
            prop_kernel<<<pb, 256, 0, stream>>>(P.slot[(k - 1) % 3],
                                                P.slot[k % 3],
                                                P.row_ptr, P.edat);
            if (k == 2) launch_fc1(0, 3, 0, 0);
            if (k == 5) launch_fc1(0, 3, 3, 1);
        }
        launch_fc1(0, 3, 6, 3);
    }

    bn_finalize<<<1, 512, 0, stream>>>(P.gsum, P.gsq, gamma, beta, W2, b2,
                                       P.w2s, P.cvec);
    fc2_kernel<<<(NNODES / 16 * 64 + 255) / 256, 256, 0, stream>>>(P.h1acc, P.w2s,
                                                                   P.cvec, out);
}

// Round 16
// 899.104 us; speedup vs baseline: 1.0878x; 1.0043x over previous
//
#include <hip/hip_runtime.h>
#include <hip/hip_bf16.h>
#include <cstdint>
#include <cstddef>

#define NNODES 100000
#define DFEAT 128
#define KHOP 8
#define FAN1 1152        // D*(K+1)
#define HIDN 512
#define OUTD 32
#define NEDGE 1600000
#define BN_EPS 1e-5f
#define DEG_EPS 1e-8f
#define FIXSCALE 67108864.0f   // 2^26

using short8 = __attribute__((ext_vector_type(8))) short;
using f32x4  = __attribute__((ext_vector_type(4))) float;

__device__ __forceinline__ float bf16lo(uint32_t u) { return __uint_as_float(u << 16); }
__device__ __forceinline__ float bf16hi(uint32_t u) { return __uint_as_float(u & 0xffff0000u); }
__device__ __forceinline__ float bf16s(short x) {
    return __uint_as_float(((uint32_t)(uint16_t)x) << 16);
}
__device__ __forceinline__ uint32_t packbf(float a, float b) {
    uint32_t lo = __bfloat16_as_ushort(__float2bfloat16(a));
    uint32_t hi = __bfloat16_as_ushort(__float2bfloat16(b));
    return lo | (hi << 16);
}

__device__ __forceinline__ void gload16(const void* g, void* l) {
    __builtin_amdgcn_global_load_lds(
        (const __attribute__((address_space(1))) uint32_t*)g,
        (__attribute__((address_space(3))) uint32_t*)l, 16, 0, 0);
}

struct Blk5 { const __hip_bfloat16* p[5]; };

// ------ edge pass 1: ONE packed 64-bit atomic = {cnt:16 | deg_fix:48} ------
__global__ __launch_bounds__(256) void edge_kernel(
    const int* __restrict__ ei, const float* __restrict__ coor,
    const float* __restrict__ theta, const int* __restrict__ mm,
    unsigned long long* __restrict__ packed, unsigned short* __restrict__ rank)
{
    int e = blockIdx.x * 256 + threadIdx.x;
    if (e >= NEDGE) return;
    float tom = theta[0] / (float)mm[0];
    int r = ei[e], c = ei[NEDGE + e];
    float2 pr = *(const float2*)(coor + 2*(size_t)r);
    float2 pc = *(const float2*)(coor + 2*(size_t)c);
    float dx = pr.x - pc.x, dy = pr.y - pc.y;
    float w = expf(-(dx*dx + dy*dy) * tom);
    unsigned long long enc = (1ULL << 48)
        | (unsigned long long)(unsigned int)__float2uint_rn(w * FIXSCALE);
    unsigned long long old = atomicAdd(&packed[r], enc);
    rank[e] = (unsigned short)(old >> 48);
}

// ---------------- 3-phase parallel scan (reads counts from packed) --------
__global__ __launch_bounds__(1024) void scan_local(
    const unsigned long long* __restrict__ packed, int* __restrict__ row_ptr,
    int* __restrict__ bsum, int n)
{
    __shared__ int wsum[16];
    int b = blockIdx.x, tid = threadIdx.x;
    int i = b * 1024 + tid;
    int lane = tid & 63, wv = tid >> 6;
    int v = (i < n) ? (int)(packed[i] >> 48) : 0;
    #pragma unroll
    for (int off = 1; off < 64; off <<= 1) {
        int t = __shfl_up(v, off, 64);
        if (lane >= off) v += t;
    }
    if (lane == 63) wsum[wv] = v;
    __syncthreads();
    if (tid < 16) {
        int t = wsum[tid];
        #pragma unroll
        for (int off = 1; off < 16; off <<= 1) {
            int u = __shfl_up(t, off, 64);
            if (tid >= off) t += u;
        }
        wsum[tid] = t;
    }
    __syncthreads();
    int incl = v + ((wv == 0) ? 0 : wsum[wv - 1]);
    if (i < n) row_ptr[i + 1] = incl;
    if (tid == 0) bsum[b] = wsum[15];
}

__global__ __launch_bounds__(128) void scan_carry(int* __restrict__ bsum, int n)
{
    __shared__ int ws[2];
    int tid = threadIdx.x, lane = tid & 63, wv = tid >> 6;
    int v = (tid < n) ? bsum[tid] : 0;
    int incl = v;
    #pragma unroll
    for (int off = 1; off < 64; off <<= 1) {
        int t = __shfl_up(incl, off, 64);
        if (lane >= off) incl += t;
    }
    if (lane == 63) ws[wv] = incl;
    __syncthreads();
    int excl = incl - v + ((wv == 0) ? 0 : ws[0]);
    if (tid < n) bsum[tid] = excl;
}

__global__ __launch_bounds__(256) void scan_add(
    const int* __restrict__ bsum, int* __restrict__ row_ptr, int n)
{
    int i = blockIdx.x * 256 + threadIdx.x;
    if (i == 0) row_ptr[0] = 0;
    if (i < n) row_ptr[i + 1] += bsum[i >> 10];
}

// ------ edge pass 2: ATOMIC-FREE fill; packed edge data {col, nrm} --------
__global__ __launch_bounds__(256) void fill_kernel(
    const int* __restrict__ ei, const float* __restrict__ coor,
    const float* __restrict__ theta, const int* __restrict__ mm,
    const unsigned long long* __restrict__ packed,
    const unsigned short* __restrict__ rank, const int* __restrict__ row_ptr,
    uint2* __restrict__ edat)
{
    int e = blockIdx.x * 256 + threadIdx.x;
    if (e >= NEDGE) return;
    float tom = theta[0] / (float)mm[0];
    int r = ei[e], c = ei[NEDGE + e];
    float2 pr = *(const float2*)(coor + 2*(size_t)r);
    float2 pc = *(const float2*)(coor + 2*(size_t)c);
    float dx = pr.x - pc.x, dy = pr.y - pc.y;
    float w = expf(-(dx*dx + dy*dy) * tom);
    float deg = (float)(double)(packed[r] & 0xFFFFFFFFFFFFULL) * (1.0f / FIXSCALE);
    int pos = row_ptr[r] + rank[e];
    uint2 d;
    d.x = (unsigned)c;
    d.y = __float_as_uint(w / (deg + DEG_EPS));
    edat[pos] = d;
}

// ---------------- cast feature -> bf16 slot ([N,128]) ----------------
__global__ __launch_bounds__(256) void cast_feat_kernel(
    const float* __restrict__ f, __hip_bfloat16* __restrict__ x0)
{
    int i = blockIdx.x * 256 + threadIdx.x;      // over N*64 float2 units
    int node = i >> 6, l2 = i & 63;
    if (node >= NNODES) return;
    float2 v = *(const float2*)(f + (size_t)node * DFEAT + l2 * 2);
    __hip_bfloat162 hb;
    hb.x = __float2bfloat16(v.x);
    hb.y = __float2bfloat16(v.y);
    *(__hip_bfloat162*)(x0 + (size_t)node * DFEAT + l2 * 2) = hb;
}

// ---------------- cast W1 -> bf16 ----------------
__global__ __launch_bounds__(256) void cast_w1_kernel(
    const float* __restrict__ w1, __hip_bfloat16* __restrict__ o)
{
    int i = blockIdx.x * 256 + threadIdx.x;
    if (i < HIDN * FAN1) o[i] = __float2bfloat16(w1[i]);
}

// ------- prop hop: wave/node; 4 quarter-lanes own edge streams, 16B/lane ---
__global__ __launch_bounds__(256) void prop_kernel(
    const __hip_bfloat16* __restrict__ x, __hip_bfloat16* __restrict__ y,
    const int* __restrict__ row_ptr, const uint2* __restrict__ edat)
{
    int gw = (blockIdx.x * 256 + threadIdx.x) >> 6;
    if (gw >= NNODES) return;
    int lane = threadIdx.x & 63;
    int q = lane >> 4, sl = lane & 15;
    int beg = row_ptr[gw], end = row_ptr[gw + 1];
    float a0 = 0.f, a1 = 0.f, a2 = 0.f, a3 = 0.f;
    float a4 = 0.f, a5 = 0.f, a6 = 0.f, a7 = 0.f;
    int e = beg + q;
    for (; e + 12 < end; e += 16) {   // this lane: e, e+4, e+8, e+12
        uint2 e0 = edat[e], e1 = edat[e + 4], e2 = edat[e + 8], e3 = edat[e + 12];
        float w0 = __uint_as_float(e0.y), w1 = __uint_as_float(e1.y);
        float w2 = __uint_as_float(e2.y), w3 = __uint_as_float(e3.y);
        uint4 u0 = *(const uint4*)(x + (size_t)e0.x * DFEAT + sl * 8);
        uint4 u1 = *(const uint4*)(x + (size_t)e1.x * DFEAT + sl * 8);
        uint4 u2 = *(const uint4*)(x + (size_t)e2.x * DFEAT + sl * 8);
        uint4 u3 = *(const uint4*)(x + (size_t)e3.x * DFEAT + sl * 8);
        a0 += w0 * bf16lo(u0.x); a1 += w0 * bf16hi(u0.x);
        a2 += w0 * bf16lo(u0.y); a3 += w0 * bf16hi(u0.y);
        a4 += w0 * bf16lo(u0.z); a5 += w0 * bf16hi(u0.z);
        a6 += w0 * bf16lo(u0.w); a7 += w0 * bf16hi(u0.w);
        a0 += w1 * bf16lo(u1.x); a1 += w1 * bf16hi(u1.x);
        a2 += w1 * bf16lo(u1.y); a3 += w1 * bf16hi(u1.y);
        a4 += w1 * bf16lo(u1.z); a5 += w1 * bf16hi(u1.z);
        a6 += w1 * bf16lo(u1.w); a7 += w1 * bf16hi(u1.w);
        a0 += w2 * bf16lo(u2.x); a1 += w2 * bf16hi(u2.x);
        a2 += w2 * bf16lo(u2.y); a3 += w2 * bf16hi(u2.y);
        a4 += w2 * bf16lo(u2.z); a5 += w2 * bf16hi(u2.z);
        a6 += w2 * bf16lo(u2.w); a7 += w2 * bf16hi(u2.w);
        a0 += w3 * bf16lo(u3.x); a1 += w3 * bf16hi(u3.x);
        a2 += w3 * bf16lo(u3.y); a3 += w3 * bf16hi(u3.y);
        a4 += w3 * bf16lo(u3.z); a5 += w3 * bf16hi(u3.z);
        a6 += w3 * bf16lo(u3.w); a7 += w3 * bf16hi(u3.w);
    }
    for (; e < end; e += 4) {
        uint2 e0 = edat[e];
        float w0 = __uint_as_float(e0.y);
        uint4 u0 = *(const uint4*)(x + (size_t)e0.x * DFEAT + sl * 8);
        a0 += w0 * bf16lo(u0.x); a1 += w0 * bf16hi(u0.x);
        a2 += w0 * bf16lo(u0.y); a3 += w0 * bf16hi(u0.y);
        a4 += w0 * bf16lo(u0.z); a5 += w0 * bf16hi(u0.z);
        a6 += w0 * bf16lo(u0.w); a7 += w0 * bf16hi(u0.w);
    }
    a0 += __shfl_xor(a0, 16, 64); a0 += __shfl_xor(a0, 32, 64);
    a1 += __shfl_xor(a1, 16, 64); a1 += __shfl_xor(a1, 32, 64);
    a2 += __shfl_xor(a2, 16, 64); a2 += __shfl_xor(a2, 32, 64);
    a3 += __shfl_xor(a3, 16, 64); a3 += __shfl_xor(a3, 32, 64);
    a4 += __shfl_xor(a4, 16, 64); a4 += __shfl_xor(a4, 32, 64);
    a5 += __shfl_xor(a5, 16, 64); a5 += __shfl_xor(a5, 32, 64);
    a6 += __shfl_xor(a6, 16, 64); a6 += __shfl_xor(a6, 32, 64);
    a7 += __shfl_xor(a7, 16, 64); a7 += __shfl_xor(a7, 32, 64);
    if (q == 0) {
        uint4 o;
        o.x = packbf(a0, a1);
        o.y = packbf(a2, a3);
        o.z = packbf(a4, a5);
        o.w = packbf(a6, a7);
        *(uint4*)(y + (size_t)gw * DFEAT + sl * 8) = o;
    }
}

// ---- fc1: r12 core (128x128, BK=32, linear dbuf, vmcnt(4)) + ZERO-COST
//      XOR swizzle: slot u holds chunk (u&3)^((u>>3)&3); both the staging
//      source offset and the fragment-read chunk are per-lane CONSTANTS.
//      h1 N-BLOCK-MAJOR [4][N][128] streaming epilogue. ----
// grid 3128 = 8 XCD chunks x 391; lid = (pid%8)*391 + pid/8; n-fast
// mode bit0 = RMW accumulate, bit1 = finalize (bias+lrelu+stats)
__global__ __launch_bounds__(256) void fc1_kernel(
    Blk5 blks, const __hip_bfloat16* __restrict__ w1,
    const float* __restrict__ b1, __hip_bfloat16* __restrict__ h1b,
    float* __restrict__ gsum, float* __restrict__ gsq,
    int nkt, int kb0, int mode)
{
    __shared__ char smem[33792];   // dbuf: 2 x (A 8K | B 8K); epilogue: 32K tile + 1K stats
    int pid = blockIdx.x;
    int lid = (pid & 7) * 391 + (pid >> 3);   // XCD-chunked bijective remap
    int n0 = (lid & 3) * 128;
    int m0 = (lid >> 2) * 128;
    int tid = threadIdx.x, lane = tid & 63, wv = tid >> 6;
    int wr = wv >> 1, wc = wv & 1;
    // per-lane constant swizzles (zero loop cost):
    int sq = (lane & 3) ^ ((lane >> 3) & 3);        // staging source chunk
    int rch = (lane >> 4) ^ (((lane & 15) >> 1) & 3); // fragment read chunk

    f32x4 acc[4][4];
    #pragma unroll
    for (int i = 0; i < 4; ++i)
        #pragma unroll
        for (int j = 0; j < 4; ++j)
            acc[i][j] = (f32x4){0.f, 0.f, 0.f, 0.f};

// Swizzled staging: LDS slot u (linear dest) <- global chunk (u&3)^((u>>3)&3).
// For u = l*256 + wv*64 + lane this chunk index == sq (per-lane const).
#define STAGE(hb, ktv) do {                                                   \
        const __hip_bfloat16* xp = blks.p[(ktv) >> 2];                        \
        int koff_ = ((ktv) & 3) * 32;                                         \
        int kglob_ = (kb0 + ((ktv) >> 2)) * 128 + koff_;                      \
        char* Ab_ = smem + (hb) * 16384;                                      \
        char* Bb_ = Ab_ + 8192;                                               \
        _Pragma("unroll")                                                     \
        for (int l = 0; l < 2; ++l) {                                         \
            int u = l * 256 + wv * 64 + lane;                                 \
            int row_ = u >> 2;                                                \
            gload16(xp + (size_t)(m0 + row_) * DFEAT + koff_ + sq * 8,        \
                    Ab_ + u * 16);                                            \
            gload16(w1 + (size_t)(n0 + row_) * FAN1 + kglob_ + sq * 8,        \
                    Bb_ + u * 16);                                            \
        }                                                                     \
    } while (0)

    STAGE(0, 0);
    for (int kt = 0; kt < nkt; ++kt) {        // runtime bound: no unroll
        int cur = kt & 1;
        __builtin_amdgcn_s_barrier();          // prev compute done; buf^1 free
        if (kt + 1 < nkt) {
            STAGE(cur ^ 1, kt + 1);
            asm volatile("s_waitcnt vmcnt(4)" ::: "memory");   // cur's 4 done
        } else {
            asm volatile("s_waitcnt vmcnt(0)" ::: "memory");
        }
        __builtin_amdgcn_s_barrier();          // buf[cur] staged for all waves
        char* Ab = smem + cur * 16384;
        char* Bb = Ab + 8192;
        short8 af[4], bfr[4];
        #pragma unroll
        for (int i = 0; i < 4; ++i)
            af[i] = *(const short8*)(Ab + (wr * 64 + i * 16 + (lane & 15)) * 64 + rch * 16);
        #pragma unroll
        for (int j = 0; j < 4; ++j)
            bfr[j] = *(const short8*)(Bb + (wc * 64 + j * 16 + (lane & 15)) * 64 + rch * 16);
        #pragma unroll
        for (int j = 0; j < 4; ++j)
            #pragma unroll
            for (int i = 0; i < 4; ++i)
                acc[i][j] = __builtin_amdgcn_mfma_f32_16x16x32_bf16(af[i], bfr[j], acc[i][j], 0, 0, 0);
    }
#undef STAGE

    // ---- epilogue: LDS transpose; STREAMING store to blocked h1 ----
    __syncthreads();
    __hip_bfloat16* tile = (__hip_bfloat16*)smem;      // [128][128]
    float* lsum = (float*)(smem + 32768);              // [128]
    float* lsq  = lsum + 128;
    bool fin = (mode & 2) != 0;
    if (fin && tid < 128) { lsum[tid] = 0.f; lsq[tid] = 0.f; }
    #pragma unroll
    for (int i = 0; i < 4; ++i) {
        #pragma unroll
        for (int j = 0; j < 4; ++j) {
            int col = wc * 64 + j * 16 + (lane & 15);
            #pragma unroll
            for (int r = 0; r < 4; ++r) {
                int row = wr * 64 + i * 16 + (lane >> 4) * 4 + r;
                tile[row * 128 + col] = __float2bfloat16(acc[i][j][r]);
            }
        }
    }
    __syncthreads();

    int cu = tid & 15, tr = tid >> 4;
    float bias[8];
    float s[8], q[8];
    #pragma unroll
    for (int e = 0; e < 8; ++e) { s[e] = 0.f; q[e] = 0.f; }
    if (fin) {
        #pragma unroll
        for (int e = 0; e < 8; ++e) bias[e] = b1[n0 + cu * 8 + e];
    }
    size_t blkbase = (size_t)(n0 >> 7) * NNODES * 128;
    for (int p = 0; p < 8; ++p) {
        int row = p * 16 + tr;
        int gm = m0 + row;
        if (gm >= NNODES) continue;
        short8 fresh = *(const short8*)(tile + row * 128 + cu * 8);
        size_t gidx = blkbase + (size_t)gm * 128 + cu * 8;   // streaming: 256B/row
        float v[8];
        #pragma unroll
        for (int e = 0; e < 8; ++e) v[e] = bf16s(fresh[e]);
        if (mode & 1) {
            short8 prev = *(const short8*)(h1b + gidx);
            #pragma unroll
            for (int e = 0; e < 8; ++e) v[e] += bf16s(prev[e]);
        }
        if (fin) {
            #pragma unroll
            for (int e = 0; e < 8; ++e) {
                float t = v[e] + bias[e];
                t = (t > 0.f) ? t : 0.2f * t;
                v[e] = t;
                s[e] += t;
                q[e] += t * t;
            }
        }
        short8 outv;
        #pragma unroll
        for (int e = 0; e < 8; ++e) outv[e] = (short)__bfloat16_as_ushort(__float2bfloat16(v[e]));
        *(short8*)(h1b + gidx) = outv;
    }
    if (fin) {
        #pragma unroll
        for (int e = 0; e < 8; ++e) {
            atomicAdd(&lsum[cu * 8 + e], s[e]);
            atomicAdd(&lsq[cu * 8 + e], q[e]);
        }
        __syncthreads();
        if (tid < 128) {
            atomicAdd(&gsum[n0 + tid], lsum[tid]);
            atomicAdd(&gsq[n0 + tid], lsq[tid]);
        }
    }
}

// ---------------- BN finalize: fold into W2 + const vector ----------------
__global__ __launch_bounds__(512) void bn_finalize(
    const float* __restrict__ gsum, const float* __restrict__ gsq,
    const float* __restrict__ gamma, const float* __restrict__ beta,
    const float* __restrict__ w2, const float* __restrict__ b2,
    __hip_bfloat16* __restrict__ w2s, float* __restrict__ cvec)
{
    __shared__ float ts[HIDN];
    int tid = threadIdx.x;              // 512 threads
    float mu = gsum[tid] * (1.0f / NNODES);
    float var = gsq[tid] * (1.0f / NNODES) - mu * mu;
    float s = gamma[tid] * rsqrtf(var + BN_EPS);
    float t = beta[tid] - mu * s;
    ts[tid] = t;
    for (int o = 0; o < OUTD; ++o)
        w2s[o * HIDN + tid] = __float2bfloat16(w2[o * HIDN + tid] * s);
    __syncthreads();
    int lane = tid & 63, wv = tid >> 6; // 8 waves
    for (int o = wv; o < OUTD; o += 8) {
        float p = 0.f;
        for (int j = lane; j < HIDN; j += 64) p += ts[j] * w2[o * HIDN + j];
        #pragma unroll
        for (int off = 32; off; off >>= 1) p += __shfl_xor(p, off, 64);
        if (lane == 0) cvec[o] = p + b2[o];
    }
}

// ---------------- fc2: blocked h1 [4][N][128] x W2^T -> out [N,32] ---------
__global__ __launch_bounds__(256) void fc2_kernel(
    const __hip_bfloat16* __restrict__ h1b, const __hip_bfloat16* __restrict__ w2s,
    const float* __restrict__ cvec, float* __restrict__ out)
{
    int gw = (blockIdx.x * 256 + threadIdx.x) >> 6;
    if (gw >= NNODES / 16) return;
    int lane = threadIdx.x & 63;
    int m0 = gw * 16;
    f32x4 acc[2];
    acc[0] = (f32x4){0.f, 0.f, 0.f, 0.f};
    acc[1] = (f32x4){0.f, 0.f, 0.f, 0.f};
    #pragma unroll
    for (int kt = 0; kt < HIDN / 32; ++kt) {
        int k0 = kt * 32;
        short8 a = *(const short8*)(h1b
            + ((size_t)(kt >> 2) * NNODES + (m0 + (lane & 15))) * 128
            + (kt & 3) * 32 + (lane >> 4) * 8);
        #pragma unroll
        for (int j = 0; j < 2; ++j) {
            short8 b = *(const short8*)(w2s + (size_t)(j * 16 + (lane & 15)) * HIDN + k0 + (lane >> 4) * 8);
            acc[j] = __builtin_amdgcn_mfma_f32_16x16x32_bf16(a, b, acc[j], 0, 0, 0);
        }
    }
    #pragma unroll
    for (int j = 0; j < 2; ++j) {
        int col = j * 16 + (lane & 15);
        float cadd = cvec[col];
        #pragma unroll
        for (int r = 0; r < 4; ++r) {
            int row = m0 + (lane >> 4) * 4 + r;
            out[(size_t)row * OUTD + col] = acc[j][r] + cadd;
        }
    }
}

// ---------------- host ----------------
struct Ptrs {
    float *gsum, *gsq, *cvec;
    int *row_ptr, *bsum;
    unsigned long long* packed;
    unsigned short* rank;
    uint2* edat;
    __hip_bfloat16 *slot[5], *h1acc, *w1b, *w2s;
};

// rank/packed/bsum are dead before h1acc's first write (fill+scan precede
// fc1 launch 1, which fully overwrites h1acc) -> carve them from h1acc front.
static size_t layout(char* base, int nslots, Ptrs& P) {
    char* p = base;
    auto take = [&](size_t b) {
        char* q = (char*)(((uintptr_t)p + 255) & ~(uintptr_t)255);
        p = q + b;
        return q;
    };
    P.row_ptr = (int*)  take((size_t)(NNODES + 1) * 4);
    P.edat    = (uint2*)take((size_t)NEDGE * 8);
    P.h1acc   = (__hip_bfloat16*)take((size_t)NNODES * HIDN * 2);
    {   // aliased scratch inside h1acc
        char* a = (char*)P.h1acc;
        P.rank   = (unsigned short*)a;                  a += (size_t)NEDGE * 2;
        a = (char*)(((uintptr_t)a + 255) & ~(uintptr_t)255);
        P.packed = (unsigned long long*)a;              a += (size_t)NNODES * 8;
        a = (char*)(((uintptr_t)a + 255) & ~(uintptr_t)255);
        P.bsum   = (int*)a;
    }
    P.w1b     = (__hip_bfloat16*)take((size_t)HIDN * FAN1 * 2);
    P.w2s     = (__hip_bfloat16*)take((size_t)OUTD * HIDN * 2);
    P.gsum    = (float*)take(HIDN * 4);
    P.gsq     = (float*)take(HIDN * 4);
    P.cvec    = (float*)take(OUTD * 4);
    for (int i = 0; i < 5; ++i) P.slot[i] = nullptr;
    for (int i = 0; i < nslots; ++i)   // +32KB pad: fc1 A-stage overreads last m-tile
        P.slot[i] = (__hip_bfloat16*)take((size_t)NNODES * DFEAT * 2 + 32768);
    return (size_t)(p - base);
}

extern "C" void kernel_launch(void* const* d_in, const int* in_sizes, int n_in,
                              void* d_out, int out_size, void* d_ws, size_t ws_size,
                              hipStream_t stream)
{
    const float* feature = (const float*)d_in[0];
    const float* coor    = (const float*)d_in[1];
    const float* theta   = (const float*)d_in[2];
    const float* W1      = (const float*)d_in[3];
    const float* b1      = (const float*)d_in[4];
    const float* gamma   = (const float*)d_in[5];
    const float* beta    = (const float*)d_in[6];
    const float* W2      = (const float*)d_in[7];
    const float* b2      = (const float*)d_in[8];
    const int*   ei      = (const int*)d_in[9];
    const int*   mm      = (const int*)d_in[10];
    float* out = (float*)d_out;
    (void)in_sizes; (void)n_in; (void)out_size;

    Ptrs P;
    size_t need5 = layout((char*)0, 5, P);
    int nslots = (ws_size >= need5) ? 5 : 3;
    layout((char*)d_ws, nslots, P);

    hipMemsetAsync(P.packed, 0, (size_t)NNODES * 8, stream);
    hipMemsetAsync(P.gsum,   0, HIDN * 4, stream);
    hipMemsetAsync(P.gsq,    0, HIDN * 4, stream);

    int eb = (NEDGE + 255) / 256;
    int nchunk = (NNODES + 1023) / 1024;
    edge_kernel<<<eb, 256, 0, stream>>>(ei, coor, theta, mm, P.packed, P.rank);
    scan_local<<<nchunk, 1024, 0, stream>>>(P.packed, P.row_ptr, P.bsum, NNODES);
    scan_carry<<<1, 128, 0, stream>>>(P.bsum, nchunk);
    scan_add<<<(NNODES + 255) / 256, 256, 0, stream>>>(P.bsum, P.row_ptr, NNODES);
    fill_kernel<<<eb, 256, 0, stream>>>(ei, coor, theta, mm, P.packed, P.rank,
                                        P.row_ptr, P.edat);

    cast_w1_kernel<<<(HIDN * FAN1 + 255) / 256, 256, 0, stream>>>(W1, P.w1b);
    cast_feat_kernel<<<(NNODES * 64) / 256, 256, 0, stream>>>(feature, P.slot[0]);

    int pb = (NNODES * 64) / 256;
    int fgrid = 8 * 391;      // 3128 blocks, XCD-chunk swizzled in-kernel

    auto launch_fc1 = [&](int first_slot, int nblk, int kb0, int mode) {
        Blk5 b;
        for (int i = 0; i < 5; ++i) b.p[i] = P.slot[0];
        for (int i = 0; i < nblk; ++i) b.p[i] = P.slot[(first_slot + i) % nslots];
        fc1_kernel<<<fgrid, 256, 0, stream>>>(b, P.w1b, b1, P.h1acc,
                                              P.gsum, P.gsq, nblk * 4, kb0, mode);
    };

    if (nslots == 5) {
        // blocks 0..4 -> slots 0..4 (after hop 4); blocks 5..8 -> slots 0..3
        for (int k = 1; k <= KHOP; ++k) {
            prop_kernel<<<pb, 256, 0, stream>>>(P.slot[(k - 1) % 5],
                                                P.slot[k % 5],
                                                P.row_ptr, P.edat);
            if (k == 4) launch_fc1(0, 5, 0, 0);
        }
        launch_fc1(0, 4, 5, 3);
    } else {
        // blocks 0..8 rotate through slots 0,1,2
        for (int k = 1; k <= KHOP; ++k) {
            prop_kernel<<<pb, 256, 0, stream>>>(P.slot[(k - 1) % 3],
                                                P.slot[k % 3],
                                                P.row_ptr, P.edat);
            if (k == 2) launch_fc1(0, 3, 0, 0);
            if (k == 5) launch_fc1(0, 3, 3, 1);
        }
        launch_fc1(0, 3, 6, 3);
    }

    bn_finalize<<<1, 512, 0, stream>>>(P.gsum, P.gsq, gamma, beta, W2, b2,
                                       P.w2s, P.cvec);
    fc2_kernel<<<(NNODES / 16 * 64 + 255) / 256, 256, 0, stream>>>(P.h1acc, P.w2s,
                                                                   P.cvec, out);
}